// Round 13
// baseline (2528.803 us; speedup 1.0000x reference)
//
#include <hip/hip_runtime.h>
#include <cstdint>
#include <cstddef>

#define B_    4
#define N_TOK 1029
#define C_    1024
#define H_    16
#define L_    8
#define HID_  4096
#define M_TOK (B_*N_TOK)   // 4116
#define MP2_  4352
#define PROWS 4224         // pbuf row stride; gemm_s M extent (33*128)
#define KVB_  128
#define KVT2_ 9
#define KPAD_ 1152

typedef float f32x4 __attribute__((ext_vector_type(4)));
typedef short bf16x8 __attribute__((ext_vector_type(8)));

__device__ __forceinline__ uint16_t f2bf(float f) {
  uint32_t u = __float_as_uint(f);
  u += 0x7fffu + ((u >> 16) & 1u);
  return (uint16_t)(u >> 16);
}

__device__ __forceinline__ int swz16(int row, int byte_in_row) {
  return row * 128 + (byte_in_row ^ ((row & 7) << 4));
}

// ---------------- fp32 -> bf16 (row-major) ----------------
__global__ __launch_bounds__(256)
void cvt_f32_bf16(const float* __restrict__ in, uint16_t* __restrict__ out, int n4) {
  int i = blockIdx.x * 256 + threadIdx.x;
  if (i < n4) {
    float4 v = reinterpret_cast<const float4*>(in)[i];
    uint64_t pk = (uint64_t)f2bf(v.x) | ((uint64_t)f2bf(v.y) << 16)
                | ((uint64_t)f2bf(v.z) << 32) | ((uint64_t)f2bf(v.w) << 48);
    reinterpret_cast<uint64_t*>(out)[i] = pk;
  }
}

// ---------------- LayerNorm (standalone; layer-0 ln1 only) ----------------
template<int OUTMODE>   // 0: bf16 out
__global__ __launch_bounds__(256)
void ln_fwd(const float* __restrict__ x, const float* __restrict__ w,
            const float* __restrict__ b, void* __restrict__ outp) {
  const int row = blockIdx.x;
  const int tid = threadIdx.x;
  const float4 v = reinterpret_cast<const float4*>(x + (size_t)row * C_)[tid];
  float s  = v.x + v.y + v.z + v.w;
  float s2 = v.x*v.x + v.y*v.y + v.z*v.z + v.w*v.w;
  #pragma unroll
  for (int d = 1; d < 64; d <<= 1) {
    s  += __shfl_xor(s, d);
    s2 += __shfl_xor(s2, d);
  }
  __shared__ float red[8];
  const int wv = tid >> 6;
  if ((tid & 63) == 0) { red[wv] = s; red[wv + 4] = s2; }
  __syncthreads();
  s  = red[0] + red[1] + red[2] + red[3];
  s2 = red[4] + red[5] + red[6] + red[7];
  const float mu = s * (1.0f / C_);
  const float rs = rsqrtf(fmaxf(s2 * (1.0f / C_) - mu * mu, 0.0f) + 1e-6f);
  const float4 wv4 = reinterpret_cast<const float4*>(w)[tid];
  const float4 bv4 = reinterpret_cast<const float4*>(b)[tid];
  const float o0 = (v.x - mu) * rs * wv4.x + bv4.x;
  const float o1 = (v.y - mu) * rs * wv4.y + bv4.y;
  const float o2 = (v.z - mu) * rs * wv4.z + bv4.z;
  const float o3 = (v.w - mu) * rs * wv4.w + bv4.w;
  uint64_t pk = (uint64_t)f2bf(o0) | ((uint64_t)f2bf(o1) << 16)
              | ((uint64_t)f2bf(o2) << 32) | ((uint64_t)f2bf(o3) << 48);
  reinterpret_cast<uint64_t*>((uint16_t*)outp + (size_t)row * C_)[tid] = pk;
}

// ---------------- fused split-K reduce + residual + LayerNorm ----------------
template<int KCH, int OUT>
__global__ __launch_bounds__(256)
void reduce_ln(const float* __restrict__ pbuf, const float* __restrict__ bias,
               float* __restrict__ xbuf, const float* __restrict__ lw,
               const float* __restrict__ lb, void* __restrict__ outp) {
  const int m = blockIdx.x;
  const int c4 = threadIdx.x;
  float4 s = reinterpret_cast<const float4*>(bias)[c4];
  #pragma unroll
  for (int kc = 0; kc < KCH; ++kc) {
    const float4 pv = reinterpret_cast<const float4*>(pbuf + ((size_t)kc * PROWS + m) * C_)[c4];
    s.x += pv.x; s.y += pv.y; s.z += pv.z; s.w += pv.w;
  }
  float4 x = reinterpret_cast<float4*>(xbuf + (size_t)m * C_)[c4];
  x.x += s.x; x.y += s.y; x.z += s.z; x.w += s.w;
  reinterpret_cast<float4*>(xbuf + (size_t)m * C_)[c4] = x;
  float ss  = x.x + x.y + x.z + x.w;
  float ss2 = x.x*x.x + x.y*x.y + x.z*x.z + x.w*x.w;
  #pragma unroll
  for (int d = 1; d < 64; d <<= 1) {
    ss  += __shfl_xor(ss, d);
    ss2 += __shfl_xor(ss2, d);
  }
  __shared__ float red[8];
  const int wv = c4 >> 6;
  if ((c4 & 63) == 0) { red[wv] = ss; red[wv + 4] = ss2; }
  __syncthreads();
  ss  = red[0] + red[1] + red[2] + red[3];
  ss2 = red[4] + red[5] + red[6] + red[7];
  const float mu = ss * (1.0f / C_);
  const float rs = rsqrtf(fmaxf(ss2 * (1.0f / C_) - mu * mu, 0.0f) + 1e-6f);
  const float4 wv4 = reinterpret_cast<const float4*>(lw)[c4];
  const float4 bv4 = reinterpret_cast<const float4*>(lb)[c4];
  const float o0 = (x.x - mu) * rs * wv4.x + bv4.x;
  const float o1 = (x.y - mu) * rs * wv4.y + bv4.y;
  const float o2 = (x.z - mu) * rs * wv4.z + bv4.z;
  const float o3 = (x.w - mu) * rs * wv4.w + bv4.w;
  if (OUT == 0) {
    uint64_t pk = (uint64_t)f2bf(o0) | ((uint64_t)f2bf(o1) << 16)
                | ((uint64_t)f2bf(o2) << 32) | ((uint64_t)f2bf(o3) << 48);
    reinterpret_cast<uint64_t*>((uint16_t*)outp + (size_t)m * C_)[c4] = pk;
  } else {
    float4 o; o.x = o0; o.y = o1; o.z = o2; o.w = o3;
    reinterpret_cast<float4*>((float*)outp + (size_t)m * C_)[c4] = o;
  }
}

// ---------------- epilogue helper ----------------
// EPI 0: qkv head-split. EPI 1: GELU -> bf16 row-major. EPI 3: fp32 partial -> pbuf.
template<int EPI>
__device__ __forceinline__ void epi_store(int m, int col, float v, int Nn, int kc,
    const float* bias, uint16_t* outb, float* pbuf,
    uint16_t* Qp, uint16_t* Kp, uint16_t* VTp) {
  if (EPI == 3) {
    pbuf[((size_t)kc * PROWS + m) * C_ + col] = v;
  } else if (EPI == 1) {
    const float vb = v + bias[col];
    const float u = -1.5957691216f * (vb + 0.044715f * vb * vb * vb);
    const float g = vb * __builtin_amdgcn_rcpf(1.0f + __expf(u));
    outb[(size_t)m * Nn + col] = f2bf(g);
  } else {  // qkv split
    if (m < M_TOK) {
      const float vb = v + bias[col];
      const int which = col >> 10;
      const int h = (col >> 6) & 15;
      const int d = col & 63;
      const int b = m / N_TOK;
      const int key = m - b * N_TOK;
      const int bh = b * 16 + h;
      if (which == 0)      Qp[((size_t)bh * KPAD_ + key) * 64 + d] = f2bf(vb * 0.125f);
      else if (which == 1) Kp[((size_t)bh * KPAD_ + key) * 64 + d] = f2bf(vb);
      else                 VTp[((size_t)bh * 64 + d) * KPAD_ + key] = f2bf(vb);
    }
  }
}

// ---------------- gemm_s: 128x256, BK=64, 8 waves (2Mx4N, wave-tile 64x64) ------
// Single-buffered 48 KB LDS, 2 blocks/CU (launch_bounds(512,4), acc->AGPR).
// T14 reg-staged prefetch: glob->reg(t+1) issued BEFORE compute(t).
template<int EPI, int SPLIT>
__global__ __launch_bounds__(512, 4)
void gemm_s(const uint16_t* __restrict__ A, const uint16_t* __restrict__ W,
            const float* __restrict__ bias, uint16_t* __restrict__ outb,
            float* __restrict__ pbuf, int Nn, int Ktot,
            uint16_t* __restrict__ Qp, uint16_t* __restrict__ Kp,
            uint16_t* __restrict__ VTp) {
  const int nbn = Nn >> 8;
  const int KC = Ktot / SPLIT;
  const int nwg = (int)gridDim.x;
  const int q8 = nwg >> 3, r8 = nwg & 7;
  const int xcd = (int)blockIdx.x & 7, pos = (int)blockIdx.x >> 3;
  const int wgid = (xcd < r8 ? xcd * (q8 + 1) : r8 * (q8 + 1) + (xcd - r8) * q8) + pos;
  const int kc  = wgid / (33 * nbn);
  const int rem = wgid % (33 * nbn);
  const int bm = rem % 33, bn = rem / 33;   // bm fastest: per-XCD blocks share bn

  const int tid = (int)threadIdx.x;
  const int l = tid & 63, w = tid >> 6;
  const int l15 = l & 15, l4 = l >> 4;
  const int wr = w >> 2, wc = w & 3;

  __shared__ char lds[49152];   // A: [0,16K) 128 rows x 128B ; B: [16K,48K) 256 rows

  const uint16_t* Ag = A + (size_t)bm * 128 * Ktot + (size_t)kc * KC;
  const uint16_t* Wg = W + (size_t)bn * 256 * Ktot + (size_t)kc * KC;

  const int srow = tid >> 3;                 // 0..63
  const int schunk = (tid & 7) ^ (srow & 7); // chunk held by slot tid&7
  const int csel0 = ((l4) ^ (l15 & 7)) << 4;
  const int csel1 = ((4 + l4) ^ (l15 & 7)) << 4;

  bf16x8 rA0, rA1, rB0, rB1, rB2, rB3;
  auto gload = [&](int toff) {
    rA0 = *(const bf16x8*)(Ag + (size_t)(srow)      * Ktot + toff + schunk * 8);
    rA1 = *(const bf16x8*)(Ag + (size_t)(64 + srow) * Ktot + toff + schunk * 8);
    rB0 = *(const bf16x8*)(Wg + (size_t)(srow)       * Ktot + toff + schunk * 8);
    rB1 = *(const bf16x8*)(Wg + (size_t)(64 + srow)  * Ktot + toff + schunk * 8);
    rB2 = *(const bf16x8*)(Wg + (size_t)(128 + srow) * Ktot + toff + schunk * 8);
    rB3 = *(const bf16x8*)(Wg + (size_t)(192 + srow) * Ktot + toff + schunk * 8);
  };

  f32x4 acc[4][4] = {};
  const int nt = KC >> 6;
  gload(0);
  for (int t = 0; t < nt; ++t) {
    __syncthreads();   // all reads of LDS (tile t-1) done
    *(bf16x8*)(lds +         tid * 16) = rA0;
    *(bf16x8*)(lds +  8192 + tid * 16) = rA1;
    *(bf16x8*)(lds + 16384 + tid * 16) = rB0;
    *(bf16x8*)(lds + 24576 + tid * 16) = rB1;
    *(bf16x8*)(lds + 32768 + tid * 16) = rB2;
    *(bf16x8*)(lds + 40960 + tid * 16) = rB3;
    __syncthreads();   // writes visible
    if (t + 1 < nt) gload((t + 1) * 64);   // hidden under compute below
    __builtin_amdgcn_sched_barrier(0);
    #pragma unroll
    for (int kk = 0; kk < 2; ++kk) {
      const int cs = kk ? csel1 : csel0;
      bf16x8 afr[4], bfr[4];
      #pragma unroll
      for (int f = 0; f < 4; ++f)
        afr[f] = *(const bf16x8*)(lds + (wr * 64 + f * 16 + l15) * 128 + cs);
      #pragma unroll
      for (int nf = 0; nf < 4; ++nf)
        bfr[nf] = *(const bf16x8*)(lds + 16384 + (wc * 64 + nf * 16 + l15) * 128 + cs);
      #pragma unroll
      for (int f = 0; f < 4; ++f)
        #pragma unroll
        for (int nf = 0; nf < 4; ++nf)
          acc[f][nf] = __builtin_amdgcn_mfma_f32_16x16x32_bf16(afr[f], bfr[nf], acc[f][nf], 0, 0, 0);
    }
  }

  #pragma unroll
  for (int nf = 0; nf < 4; ++nf) {
    const int col = bn * 256 + wc * 64 + nf * 16 + l15;
    #pragma unroll
    for (int mf = 0; mf < 4; ++mf) {
      const int mb = bm * 128 + wr * 64 + mf * 16 + l4 * 4;
      #pragma unroll
      for (int r = 0; r < 4; ++r)
        epi_store<EPI>(mb + r, col, acc[mf][nf][r], Nn, kc, bias, outb, pbuf,
                       Qp, Kp, VTp);
    }
  }
}

// ---------------- Flash attention (swapped operands, q lane-local) ----------------
// T14: K/V tile t+1 global->reg issued before compute(t); regs->LDS at top of t+1.
__global__ __launch_bounds__(256, 3)
void attn_fwd(const uint16_t* __restrict__ Qp, const uint16_t* __restrict__ Kp,
              const uint16_t* __restrict__ VTp, uint16_t* __restrict__ ob) {
  __shared__ uint16_t Ksm_[KVB_ * 64];
  __shared__ uint16_t Vsm_[64 * KVB_];
  __shared__ uint16_t Psm_[4][16 * 136];

  const int tid = (int)threadIdx.x;
  const int l = tid & 63, w = tid >> 6;
  const int l15 = l & 15, l4 = l >> 4;
  const int bh = (int)blockIdx.x;
  const int qt = (int)blockIdx.y;

  const uint16_t* Kb = Kp + (size_t)bh * KPAD_ * 64;
  const uint16_t* Vb = VTp + (size_t)bh * 64 * KPAD_;

  bf16x8 qf[2];
  {
    const int qrow = qt * 64 + w * 16 + l15;
    const uint16_t* qbase = Qp + ((size_t)bh * KPAD_ + qrow) * 64;
    qf[0] = *(const bf16x8*)(qbase + l4 * 8);
    qf[1] = *(const bf16x8*)(qbase + 32 + l4 * 8);
  }

  float mrow = -1e30f, lrow = 0.0f;
  f32x4 oacc[4] = {};

  const int krow_s = tid >> 3;
  const int kslot_s = (tid & 7) ^ (krow_s & 7);
  const int vd_s = tid >> 4;
  const int vslot_s = (tid & 15) ^ (vd_s & 15);

  bf16x8 rK[4], rV[4];
  auto greg_load = [&](int key0) {
    #pragma unroll
    for (int it = 0; it < 4; ++it) {
      rK[it] = *(const bf16x8*)(Kb + (size_t)(key0 + it * 32 + krow_s) * 64 + kslot_s * 8);
      rV[it] = *(const bf16x8*)(Vb + (size_t)(it * 16 + vd_s) * KPAD_ + key0 + vslot_s * 8);
    }
  };

  greg_load(0);
  for (int kt = 0; kt < KVT2_; ++kt) {
    const int key0 = kt * KVB_;
    __syncthreads();   // readers of previous tile done
    #pragma unroll
    for (int it = 0; it < 4; ++it) {
      *(bf16x8*)(Ksm_ + it * 2048 + tid * 8) = rK[it];
      *(bf16x8*)(Vsm_ + it * 2048 + tid * 8) = rV[it];
    }
    __syncthreads();   // writes visible
    if (kt + 1 < KVT2_) greg_load(key0 + KVB_);   // issue-early, hidden under compute
    __builtin_amdgcn_sched_barrier(0);

    f32x4 s[8];
    #pragma unroll
    for (int kf = 0; kf < 8; ++kf) s[kf] = f32x4{0.f, 0.f, 0.f, 0.f};
    #pragma unroll
    for (int kk = 0; kk < 2; ++kk) {
      #pragma unroll
      for (int kf = 0; kf < 8; ++kf) {
        const bf16x8 kfrag = *(const bf16x8*)((const char*)Ksm_ + swz16(kf * 16 + l15, kk * 64 + l4 * 16));
        s[kf] = __builtin_amdgcn_mfma_f32_16x16x32_bf16(kfrag, qf[kk], s[kf], 0, 0, 0);
      }
    }
    if (kt == KVT2_ - 1) {
      #pragma unroll
      for (int kf = 0; kf < 8; ++kf)
        #pragma unroll
        for (int r = 0; r < 4; ++r)
          if (key0 + kf * 16 + l4 * 4 + r >= N_TOK) s[kf][r] = -1e30f;
    }
    float pmx = s[0][0];
    #pragma unroll
    for (int kf = 0; kf < 8; ++kf)
      #pragma unroll
      for (int r = 0; r < 4; ++r) pmx = fmaxf(pmx, s[kf][r]);
    pmx = fmaxf(pmx, __shfl_xor(pmx, 16));
    pmx = fmaxf(pmx, __shfl_xor(pmx, 32));
    if (!__all(pmx - mrow <= 8.0f)) {
      const float mi = fmaxf(mrow, pmx);
      const float sc = __expf(mrow - mi);
      mrow = mi;
      lrow *= sc;
      #pragma unroll
      for (int df = 0; df < 4; ++df)
        #pragma unroll
        for (int r = 0; r < 4; ++r) oacc[df][r] *= sc;
    }
    float psum = 0.0f;
    #pragma unroll
    for (int kf = 0; kf < 8; ++kf) {
      const float p0 = __expf(s[kf][0] - mrow);
      const float p1 = __expf(s[kf][1] - mrow);
      const float p2 = __expf(s[kf][2] - mrow);
      const float p3 = __expf(s[kf][3] - mrow);
      psum += (p0 + p1) + (p2 + p3);
      const uint64_t pk = (uint64_t)f2bf(p0) | ((uint64_t)f2bf(p1) << 16)
                        | ((uint64_t)f2bf(p2) << 32) | ((uint64_t)f2bf(p3) << 48);
      *(uint64_t*)(&Psm_[w][l15 * 136 + kf * 16 + l4 * 4]) = pk;
    }
    psum += __shfl_xor(psum, 16);
    psum += __shfl_xor(psum, 32);
    lrow += psum;
    #pragma unroll
    for (int kk = 0; kk < 4; ++kk) {
      const bf16x8 pf = *(const bf16x8*)(&Psm_[w][l15 * 136 + kk * 32 + l4 * 8]);
      #pragma unroll
      for (int df = 0; df < 4; ++df) {
        const int d = df * 16 + l15;
        const bf16x8 vfrag = *(const bf16x8*)(Vsm_ + d * KVB_ + (((kk * 4 + l4) ^ (d & 15)) * 8));
        oacc[df] = __builtin_amdgcn_mfma_f32_16x16x32_bf16(vfrag, pf, oacc[df], 0, 0, 0);
      }
    }
  }

  const int q = qt * 64 + w * 16 + l15;
  if (q < N_TOK) {
    const float inv = 1.0f / lrow;
    const int m = (bh >> 4) * N_TOK + q;
    const int hbase = (bh & 15) * 64;
    #pragma unroll
    for (int df = 0; df < 4; ++df)
      #pragma unroll
      for (int r = 0; r < 4; ++r) {
        const int c = hbase + df * 16 + l4 * 4 + r;
        ob[(size_t)m * C_ + c] = f2bf(oacc[df][r] * inv);
      }
  }
}

extern "C" void kernel_launch(void* const* d_in, const int* in_sizes, int n_in,
                              void* d_out, int out_size, void* d_ws, size_t ws_size,
                              hipStream_t stream) {
  const float* x_in   = (const float*)d_in[0];
  const float* ln1_w  = (const float*)d_in[1];
  const float* ln1_b  = (const float*)d_in[2];
  const float* qkv_w  = (const float*)d_in[3];
  const float* qkv_b  = (const float*)d_in[4];
  const float* proj_w = (const float*)d_in[5];
  const float* proj_b = (const float*)d_in[6];
  const float* ln2_w  = (const float*)d_in[7];
  const float* ln2_b  = (const float*)d_in[8];
  const float* fc1_w  = (const float*)d_in[9];
  const float* fc1_b  = (const float*)d_in[10];
  const float* fc2_w  = (const float*)d_in[11];
  const float* fc2_b  = (const float*)d_in[12];
  const float* norm_w = (const float*)d_in[13];
  const float* norm_b = (const float*)d_in[14];

  char* p = (char*)d_ws;
  float*    xbuf = (float*)p;     p += (size_t)MP2_ * C_ * 4;
  uint16_t* hbuf = (uint16_t*)p;  p += (size_t)MP2_ * C_ * 2;
  uint16_t* big  = (uint16_t*)p;  p += (size_t)MP2_ * HID_ * 2;
  uint16_t* wq   = (uint16_t*)p;  p += (size_t)L_ * 3 * C_ * C_ * 2;
  uint16_t* wp   = (uint16_t*)p;  p += (size_t)L_ * C_ * C_ * 2;
  uint16_t* w1   = (uint16_t*)p;  p += (size_t)L_ * HID_ * C_ * 2;
  uint16_t* w2   = (uint16_t*)p;  p += (size_t)L_ * C_ * HID_ * 2;
  uint16_t* qp   = (uint16_t*)p;  p += (size_t)64 * KPAD_ * 64 * 2;
  uint16_t* kp   = (uint16_t*)p;  p += (size_t)64 * KPAD_ * 64 * 2;
  uint16_t* vtp  = (uint16_t*)p;  p += (size_t)64 * 64 * KPAD_ * 2;
  float*    pbuf = (float*)p;     p += (size_t)4 * PROWS * C_ * 4;
  if ((size_t)(p - (char*)d_ws) > ws_size) return;

  hipMemcpyAsync(xbuf, x_in, (size_t)M_TOK * C_ * sizeof(float),
                 hipMemcpyDeviceToDevice, stream);

  auto cvt = [&](const float* src, uint16_t* dst, size_t n) {
    const int n4 = (int)(n / 4);
    cvt_f32_bf16<<<dim3((n4 + 255) / 256), dim3(256), 0, stream>>>(src, dst, n4);
  };
  cvt(qkv_w,  wq, (size_t)L_ * 3 * C_ * C_);
  cvt(proj_w, wp, (size_t)L_ * C_ * C_);
  cvt(fc1_w,  w1, (size_t)L_ * HID_ * C_);
  cvt(fc2_w,  w2, (size_t)L_ * C_ * HID_);

  // layer-0 ln1 (later layers get it fused into reduce_ln)
  ln_fwd<0><<<dim3(M_TOK), dim3(256), 0, stream>>>(xbuf, ln1_w, ln1_b, hbuf);

  for (int lyr = 0; lyr < L_; ++lyr) {
    // qkv: gemm_s (396 blocks) -> per-head panels
    gemm_s<0, 1><<<dim3(396), dim3(512), 0, stream>>>(
        hbuf, wq + (size_t)lyr * 3 * C_ * C_, qkv_b + (size_t)lyr * 3 * C_,
        nullptr, nullptr, 3 * C_, C_, qp, kp, vtp);
    attn_fwd<<<dim3(64, 17), dim3(256), 0, stream>>>(qp, kp, vtp, hbuf);
    // proj: split4 (528 blocks, 2/CU stagger) -> pbuf; fused reduce + ln2
    gemm_s<3, 4><<<dim3(528), dim3(512), 0, stream>>>(
        hbuf, wp + (size_t)lyr * C_ * C_, nullptr, nullptr, pbuf, C_, C_,
        nullptr, nullptr, nullptr);
    reduce_ln<4, 0><<<dim3(M_TOK), dim3(256), 0, stream>>>(
        pbuf, proj_b + (size_t)lyr * C_, xbuf,
        ln2_w + (size_t)lyr * C_, ln2_b + (size_t)lyr * C_, hbuf);
    // fc1: direct, GELU -> big
    gemm_s<1, 1><<<dim3(528), dim3(512), 0, stream>>>(
        hbuf, w1 + (size_t)lyr * HID_ * C_, fc1_b + (size_t)lyr * HID_,
        big, nullptr, HID_, C_, nullptr, nullptr, nullptr);
    // fc2: split4 -> pbuf; fused reduce + (ln1[next] | final norm)
    gemm_s<3, 4><<<dim3(528), dim3(512), 0, stream>>>(
        big, w2 + (size_t)lyr * C_ * HID_, nullptr, nullptr, pbuf, C_, HID_,
        nullptr, nullptr, nullptr);
    if (lyr < L_ - 1) {
      reduce_ln<4, 0><<<dim3(M_TOK), dim3(256), 0, stream>>>(
          pbuf, fc2_b + (size_t)lyr * C_, xbuf,
          ln1_w + (size_t)(lyr + 1) * C_, ln1_b + (size_t)(lyr + 1) * C_, hbuf);
    } else {
      reduce_ln<4, 1><<<dim3(M_TOK), dim3(256), 0, stream>>>(
          pbuf, fc2_b + (size_t)lyr * C_, xbuf, norm_w, norm_b, d_out);
    }
  }
}

// Round 14
// 2471.164 us; speedup vs baseline: 1.0233x; 1.0233x over previous
//
#include <hip/hip_runtime.h>
#include <cstdint>
#include <cstddef>

#define B_    4
#define N_TOK 1029
#define C_    1024
#define H_    16
#define L_    8
#define HID_  4096
#define M_TOK (B_*N_TOK)   // 4116
#define MP2_  4352
#define PROWS 4224         // pbuf row stride; gemm_s M extent (33*128)
#define KVB_  128
#define KVT2_ 9
#define KPAD_ 1152

typedef float f32x4 __attribute__((ext_vector_type(4)));
typedef short bf16x8 __attribute__((ext_vector_type(8)));

__device__ __forceinline__ uint16_t f2bf(float f) {
  uint32_t u = __float_as_uint(f);
  u += 0x7fffu + ((u >> 16) & 1u);
  return (uint16_t)(u >> 16);
}

__device__ __forceinline__ void async_copy16(const uint16_t* src, uint16_t* lds_dst) {
  __builtin_amdgcn_global_load_lds(
      (const __attribute__((address_space(1))) void*)src,
      (__attribute__((address_space(3))) void*)lds_dst, 16, 0, 0);
}

__device__ __forceinline__ int swz16(int row, int byte_in_row) {
  return row * 128 + (byte_in_row ^ ((row & 7) << 4));
}

// ---------------- fp32 -> bf16 (row-major) ----------------
__global__ __launch_bounds__(256)
void cvt_f32_bf16(const float* __restrict__ in, uint16_t* __restrict__ out, int n4) {
  int i = blockIdx.x * 256 + threadIdx.x;
  if (i < n4) {
    float4 v = reinterpret_cast<const float4*>(in)[i];
    uint64_t pk = (uint64_t)f2bf(v.x) | ((uint64_t)f2bf(v.y) << 16)
                | ((uint64_t)f2bf(v.z) << 32) | ((uint64_t)f2bf(v.w) << 48);
    reinterpret_cast<uint64_t*>(out)[i] = pk;
  }
}

// ---------------- LayerNorm (standalone; layer-0 ln1 only) ----------------
template<int OUTMODE>   // 0: bf16 out
__global__ __launch_bounds__(256)
void ln_fwd(const float* __restrict__ x, const float* __restrict__ w,
            const float* __restrict__ b, void* __restrict__ outp) {
  const int row = blockIdx.x;
  const int tid = threadIdx.x;
  const float4 v = reinterpret_cast<const float4*>(x + (size_t)row * C_)[tid];
  float s  = v.x + v.y + v.z + v.w;
  float s2 = v.x*v.x + v.y*v.y + v.z*v.z + v.w*v.w;
  #pragma unroll
  for (int d = 1; d < 64; d <<= 1) {
    s  += __shfl_xor(s, d);
    s2 += __shfl_xor(s2, d);
  }
  __shared__ float red[8];
  const int wv = tid >> 6;
  if ((tid & 63) == 0) { red[wv] = s; red[wv + 4] = s2; }
  __syncthreads();
  s  = red[0] + red[1] + red[2] + red[3];
  s2 = red[4] + red[5] + red[6] + red[7];
  const float mu = s * (1.0f / C_);
  const float rs = rsqrtf(fmaxf(s2 * (1.0f / C_) - mu * mu, 0.0f) + 1e-6f);
  const float4 wv4 = reinterpret_cast<const float4*>(w)[tid];
  const float4 bv4 = reinterpret_cast<const float4*>(b)[tid];
  const float o0 = (v.x - mu) * rs * wv4.x + bv4.x;
  const float o1 = (v.y - mu) * rs * wv4.y + bv4.y;
  const float o2 = (v.z - mu) * rs * wv4.z + bv4.z;
  const float o3 = (v.w - mu) * rs * wv4.w + bv4.w;
  uint64_t pk = (uint64_t)f2bf(o0) | ((uint64_t)f2bf(o1) << 16)
              | ((uint64_t)f2bf(o2) << 32) | ((uint64_t)f2bf(o3) << 48);
  reinterpret_cast<uint64_t*>((uint16_t*)outp + (size_t)row * C_)[tid] = pk;
}

// ---------------- fused split-K reduce + residual + LayerNorm ----------------
template<int KCH, int OUT>
__global__ __launch_bounds__(256)
void reduce_ln(const float* __restrict__ pbuf, const float* __restrict__ bias,
               float* __restrict__ xbuf, const float* __restrict__ lw,
               const float* __restrict__ lb, void* __restrict__ outp) {
  const int m = blockIdx.x;
  const int c4 = threadIdx.x;
  float4 s = reinterpret_cast<const float4*>(bias)[c4];
  #pragma unroll
  for (int kc = 0; kc < KCH; ++kc) {
    const float4 pv = reinterpret_cast<const float4*>(pbuf + ((size_t)kc * PROWS + m) * C_)[c4];
    s.x += pv.x; s.y += pv.y; s.z += pv.z; s.w += pv.w;
  }
  float4 x = reinterpret_cast<float4*>(xbuf + (size_t)m * C_)[c4];
  x.x += s.x; x.y += s.y; x.z += s.z; x.w += s.w;
  reinterpret_cast<float4*>(xbuf + (size_t)m * C_)[c4] = x;
  float ss  = x.x + x.y + x.z + x.w;
  float ss2 = x.x*x.x + x.y*x.y + x.z*x.z + x.w*x.w;
  #pragma unroll
  for (int d = 1; d < 64; d <<= 1) {
    ss  += __shfl_xor(ss, d);
    ss2 += __shfl_xor(ss2, d);
  }
  __shared__ float red[8];
  const int wv = c4 >> 6;
  if ((c4 & 63) == 0) { red[wv] = ss; red[wv + 4] = ss2; }
  __syncthreads();
  ss  = red[0] + red[1] + red[2] + red[3];
  ss2 = red[4] + red[5] + red[6] + red[7];
  const float mu = ss * (1.0f / C_);
  const float rs = rsqrtf(fmaxf(ss2 * (1.0f / C_) - mu * mu, 0.0f) + 1e-6f);
  const float4 wv4 = reinterpret_cast<const float4*>(lw)[c4];
  const float4 bv4 = reinterpret_cast<const float4*>(lb)[c4];
  const float o0 = (x.x - mu) * rs * wv4.x + bv4.x;
  const float o1 = (x.y - mu) * rs * wv4.y + bv4.y;
  const float o2 = (x.z - mu) * rs * wv4.z + bv4.z;
  const float o3 = (x.w - mu) * rs * wv4.w + bv4.w;
  if (OUT == 0) {
    uint64_t pk = (uint64_t)f2bf(o0) | ((uint64_t)f2bf(o1) << 16)
                | ((uint64_t)f2bf(o2) << 32) | ((uint64_t)f2bf(o3) << 48);
    reinterpret_cast<uint64_t*>((uint16_t*)outp + (size_t)m * C_)[c4] = pk;
  } else {
    float4 o; o.x = o0; o.y = o1; o.z = o2; o.w = o3;
    reinterpret_cast<float4*>((float*)outp + (size_t)m * C_)[c4] = o;
  }
}

// ---------------- epilogue helper ----------------
// EPI 0: qkv head-split. EPI 1: GELU -> bf16 row-major. EPI 3: fp32 partial -> pbuf.
template<int EPI>
__device__ __forceinline__ void epi_store(int m, int col, float v, int Nn, int kc,
    const float* bias, uint16_t* outb, float* pbuf,
    uint16_t* Qp, uint16_t* Kp, uint16_t* VTp) {
  if (EPI == 3) {
    pbuf[((size_t)kc * PROWS + m) * C_ + col] = v;
  } else if (EPI == 1) {
    const float vb = v + bias[col];
    const float u = -1.5957691216f * (vb + 0.044715f * vb * vb * vb);
    const float g = vb * __builtin_amdgcn_rcpf(1.0f + __expf(u));
    outb[(size_t)m * Nn + col] = f2bf(g);
  } else {  // qkv split
    if (m < M_TOK) {
      const float vb = v + bias[col];
      const int which = col >> 10;
      const int h = (col >> 6) & 15;
      const int d = col & 63;
      const int b = m / N_TOK;
      const int key = m - b * N_TOK;
      const int bh = b * 16 + h;
      if (which == 0)      Qp[((size_t)bh * KPAD_ + key) * 64 + d] = f2bf(vb * 0.125f);
      else if (which == 1) Kp[((size_t)bh * KPAD_ + key) * 64 + d] = f2bf(vb);
      else                 VTp[((size_t)bh * 64 + d) * KPAD_ + key] = f2bf(vb);
    }
  }
}

// ---------------- gemm_s: 128x256, BK=64, 8 waves (2Mx4N, wave-tile 64x64) ------
// Single-buffered 48 KB LDS, 2 blocks/CU (launch_bounds(512,4), acc->AGPR).
// T14 reg-staged prefetch: glob->reg(t+1) issued BEFORE compute(t).
template<int EPI, int SPLIT>
__global__ __launch_bounds__(512, 4)
void gemm_s(const uint16_t* __restrict__ A, const uint16_t* __restrict__ W,
            const float* __restrict__ bias, uint16_t* __restrict__ outb,
            float* __restrict__ pbuf, int Nn, int Ktot,
            uint16_t* __restrict__ Qp, uint16_t* __restrict__ Kp,
            uint16_t* __restrict__ VTp) {
  const int nbn = Nn >> 8;
  const int KC = Ktot / SPLIT;
  const int nwg = (int)gridDim.x;
  const int q8 = nwg >> 3, r8 = nwg & 7;
  const int xcd = (int)blockIdx.x & 7, pos = (int)blockIdx.x >> 3;
  const int wgid = (xcd < r8 ? xcd * (q8 + 1) : r8 * (q8 + 1) + (xcd - r8) * q8) + pos;
  const int kc  = wgid / (33 * nbn);
  const int rem = wgid % (33 * nbn);
  const int bm = rem % 33, bn = rem / 33;   // bm fastest: per-XCD blocks share bn

  const int tid = (int)threadIdx.x;
  const int l = tid & 63, w = tid >> 6;
  const int l15 = l & 15, l4 = l >> 4;
  const int wr = w >> 2, wc = w & 3;

  __shared__ char lds[49152];   // A: [0,16K) 128 rows x 128B ; B: [16K,48K) 256 rows

  const uint16_t* Ag = A + (size_t)bm * 128 * Ktot + (size_t)kc * KC;
  const uint16_t* Wg = W + (size_t)bn * 256 * Ktot + (size_t)kc * KC;

  const int srow = tid >> 3;                 // 0..63
  const int schunk = (tid & 7) ^ (srow & 7); // chunk held by slot tid&7
  const int csel0 = ((l4) ^ (l15 & 7)) << 4;
  const int csel1 = ((4 + l4) ^ (l15 & 7)) << 4;

  bf16x8 rA0, rA1, rB0, rB1, rB2, rB3;
  auto gload = [&](int toff) {
    rA0 = *(const bf16x8*)(Ag + (size_t)(srow)      * Ktot + toff + schunk * 8);
    rA1 = *(const bf16x8*)(Ag + (size_t)(64 + srow) * Ktot + toff + schunk * 8);
    rB0 = *(const bf16x8*)(Wg + (size_t)(srow)       * Ktot + toff + schunk * 8);
    rB1 = *(const bf16x8*)(Wg + (size_t)(64 + srow)  * Ktot + toff + schunk * 8);
    rB2 = *(const bf16x8*)(Wg + (size_t)(128 + srow) * Ktot + toff + schunk * 8);
    rB3 = *(const bf16x8*)(Wg + (size_t)(192 + srow) * Ktot + toff + schunk * 8);
  };

  f32x4 acc[4][4] = {};
  const int nt = KC >> 6;
  gload(0);
  for (int t = 0; t < nt; ++t) {
    __syncthreads();   // all reads of LDS (tile t-1) done
    *(bf16x8*)(lds +         tid * 16) = rA0;
    *(bf16x8*)(lds +  8192 + tid * 16) = rA1;
    *(bf16x8*)(lds + 16384 + tid * 16) = rB0;
    *(bf16x8*)(lds + 24576 + tid * 16) = rB1;
    *(bf16x8*)(lds + 32768 + tid * 16) = rB2;
    *(bf16x8*)(lds + 40960 + tid * 16) = rB3;
    __syncthreads();   // writes visible
    if (t + 1 < nt) gload((t + 1) * 64);   // hidden under compute below
    __builtin_amdgcn_sched_barrier(0);
    #pragma unroll
    for (int kk = 0; kk < 2; ++kk) {
      const int cs = kk ? csel1 : csel0;
      bf16x8 afr[4], bfr[4];
      #pragma unroll
      for (int f = 0; f < 4; ++f)
        afr[f] = *(const bf16x8*)(lds + (wr * 64 + f * 16 + l15) * 128 + cs);
      #pragma unroll
      for (int nf = 0; nf < 4; ++nf)
        bfr[nf] = *(const bf16x8*)(lds + 16384 + (wc * 64 + nf * 16 + l15) * 128 + cs);
      #pragma unroll
      for (int f = 0; f < 4; ++f)
        #pragma unroll
        for (int nf = 0; nf < 4; ++nf)
          acc[f][nf] = __builtin_amdgcn_mfma_f32_16x16x32_bf16(afr[f], bfr[nf], acc[f][nf], 0, 0, 0);
    }
  }

  #pragma unroll
  for (int nf = 0; nf < 4; ++nf) {
    const int col = bn * 256 + wc * 64 + nf * 16 + l15;
    #pragma unroll
    for (int mf = 0; mf < 4; ++mf) {
      const int mb = bm * 128 + wr * 64 + mf * 16 + l4 * 4;
      #pragma unroll
      for (int r = 0; r < 4; ++r)
        epi_store<EPI>(mb + r, col, acc[mf][nf][r], Nn, kc, bias, outb, pbuf,
                       Qp, Kp, VTp);
    }
  }
}

// ---------------- Flash attention (swapped operands, q lane-local) ----------------
__global__ __launch_bounds__(256, 3)
void attn_fwd(const uint16_t* __restrict__ Qp, const uint16_t* __restrict__ Kp,
              const uint16_t* __restrict__ VTp, uint16_t* __restrict__ ob) {
  __shared__ uint16_t Ksm_[KVB_ * 64];
  __shared__ uint16_t Vsm_[64 * KVB_];
  __shared__ uint16_t Psm_[4][16 * 136];

  const int tid = (int)threadIdx.x;
  const int l = tid & 63, w = tid >> 6;
  const int l15 = l & 15, l4 = l >> 4;
  const int bh = (int)blockIdx.x;
  const int qt = (int)blockIdx.y;

  const uint16_t* Kb = Kp + (size_t)bh * KPAD_ * 64;
  const uint16_t* Vb = VTp + (size_t)bh * 64 * KPAD_;

  bf16x8 qf[2];
  {
    const int qrow = qt * 64 + w * 16 + l15;
    const uint16_t* qbase = Qp + ((size_t)bh * KPAD_ + qrow) * 64;
    qf[0] = *(const bf16x8*)(qbase + l4 * 8);
    qf[1] = *(const bf16x8*)(qbase + 32 + l4 * 8);
  }

  float mrow = -1e30f, lrow = 0.0f;
  f32x4 oacc[4] = {};

  const int krow_s = tid >> 3;
  const int kslot_s = (tid & 7) ^ (krow_s & 7);
  const int vd_s = tid >> 4;
  const int vslot_s = (tid & 15) ^ (vd_s & 15);

  for (int kt = 0; kt < KVT2_; ++kt) {
    const int key0 = kt * KVB_;
    __syncthreads();
    #pragma unroll
    for (int it = 0; it < 4; ++it) {
      const int row = it * 32 + krow_s;
      async_copy16(Kb + (size_t)(key0 + row) * 64 + kslot_s * 8,
                   Ksm_ + it * 2048 + tid * 8);
    }
    #pragma unroll
    for (int it = 0; it < 4; ++it) {
      const int d = it * 16 + vd_s;
      async_copy16(Vb + (size_t)d * KPAD_ + key0 + vslot_s * 8,
                   Vsm_ + it * 2048 + tid * 8);
    }
    __syncthreads();

    f32x4 s[8];
    #pragma unroll
    for (int kf = 0; kf < 8; ++kf) s[kf] = f32x4{0.f, 0.f, 0.f, 0.f};
    #pragma unroll
    for (int kk = 0; kk < 2; ++kk) {
      #pragma unroll
      for (int kf = 0; kf < 8; ++kf) {
        const bf16x8 kfrag = *(const bf16x8*)((const char*)Ksm_ + swz16(kf * 16 + l15, kk * 64 + l4 * 16));
        s[kf] = __builtin_amdgcn_mfma_f32_16x16x32_bf16(kfrag, qf[kk], s[kf], 0, 0, 0);
      }
    }
    if (kt == KVT2_ - 1) {
      #pragma unroll
      for (int kf = 0; kf < 8; ++kf)
        #pragma unroll
        for (int r = 0; r < 4; ++r)
          if (key0 + kf * 16 + l4 * 4 + r >= N_TOK) s[kf][r] = -1e30f;
    }
    float pmx = s[0][0];
    #pragma unroll
    for (int kf = 0; kf < 8; ++kf)
      #pragma unroll
      for (int r = 0; r < 4; ++r) pmx = fmaxf(pmx, s[kf][r]);
    pmx = fmaxf(pmx, __shfl_xor(pmx, 16));
    pmx = fmaxf(pmx, __shfl_xor(pmx, 32));
    if (!__all(pmx - mrow <= 8.0f)) {
      const float mi = fmaxf(mrow, pmx);
      const float sc = __expf(mrow - mi);
      mrow = mi;
      lrow *= sc;
      #pragma unroll
      for (int df = 0; df < 4; ++df)
        #pragma unroll
        for (int r = 0; r < 4; ++r) oacc[df][r] *= sc;
    }
    float psum = 0.0f;
    #pragma unroll
    for (int kf = 0; kf < 8; ++kf) {
      const float p0 = __expf(s[kf][0] - mrow);
      const float p1 = __expf(s[kf][1] - mrow);
      const float p2 = __expf(s[kf][2] - mrow);
      const float p3 = __expf(s[kf][3] - mrow);
      psum += (p0 + p1) + (p2 + p3);
      const uint64_t pk = (uint64_t)f2bf(p0) | ((uint64_t)f2bf(p1) << 16)
                        | ((uint64_t)f2bf(p2) << 32) | ((uint64_t)f2bf(p3) << 48);
      *(uint64_t*)(&Psm_[w][l15 * 136 + kf * 16 + l4 * 4]) = pk;
    }
    psum += __shfl_xor(psum, 16);
    psum += __shfl_xor(psum, 32);
    lrow += psum;
    #pragma unroll
    for (int kk = 0; kk < 4; ++kk) {
      const bf16x8 pf = *(const bf16x8*)(&Psm_[w][l15 * 136 + kk * 32 + l4 * 8]);
      #pragma unroll
      for (int df = 0; df < 4; ++df) {
        const int d = df * 16 + l15;
        const bf16x8 vfrag = *(const bf16x8*)(Vsm_ + d * KVB_ + (((kk * 4 + l4) ^ (d & 15)) * 8));
        oacc[df] = __builtin_amdgcn_mfma_f32_16x16x32_bf16(vfrag, pf, oacc[df], 0, 0, 0);
      }
    }
  }

  const int q = qt * 64 + w * 16 + l15;
  if (q < N_TOK) {
    const float inv = 1.0f / lrow;
    const int m = (bh >> 4) * N_TOK + q;
    const int hbase = (bh & 15) * 64;
    #pragma unroll
    for (int df = 0; df < 4; ++df)
      #pragma unroll
      for (int r = 0; r < 4; ++r) {
        const int c = hbase + df * 16 + l4 * 4 + r;
        ob[(size_t)m * C_ + c] = f2bf(oacc[df][r] * inv);
      }
  }
}

extern "C" void kernel_launch(void* const* d_in, const int* in_sizes, int n_in,
                              void* d_out, int out_size, void* d_ws, size_t ws_size,
                              hipStream_t stream) {
  const float* x_in   = (const float*)d_in[0];
  const float* ln1_w  = (const float*)d_in[1];
  const float* ln1_b  = (const float*)d_in[2];
  const float* qkv_w  = (const float*)d_in[3];
  const float* qkv_b  = (const float*)d_in[4];
  const float* proj_w = (const float*)d_in[5];
  const float* proj_b = (const float*)d_in[6];
  const float* ln2_w  = (const float*)d_in[7];
  const float* ln2_b  = (const float*)d_in[8];
  const float* fc1_w  = (const float*)d_in[9];
  const float* fc1_b  = (const float*)d_in[10];
  const float* fc2_w  = (const float*)d_in[11];
  const float* fc2_b  = (const float*)d_in[12];
  const float* norm_w = (const float*)d_in[13];
  const float* norm_b = (const float*)d_in[14];

  char* p = (char*)d_ws;
  float*    xbuf = (float*)p;     p += (size_t)MP2_ * C_ * 4;
  uint16_t* hbuf = (uint16_t*)p;  p += (size_t)MP2_ * C_ * 2;
  uint16_t* big  = (uint16_t*)p;  p += (size_t)MP2_ * HID_ * 2;
  uint16_t* wq   = (uint16_t*)p;  p += (size_t)L_ * 3 * C_ * C_ * 2;
  uint16_t* wp   = (uint16_t*)p;  p += (size_t)L_ * C_ * C_ * 2;
  uint16_t* w1   = (uint16_t*)p;  p += (size_t)L_ * HID_ * C_ * 2;
  uint16_t* w2   = (uint16_t*)p;  p += (size_t)L_ * C_ * HID_ * 2;
  uint16_t* qp   = (uint16_t*)p;  p += (size_t)64 * KPAD_ * 64 * 2;
  uint16_t* kp   = (uint16_t*)p;  p += (size_t)64 * KPAD_ * 64 * 2;
  uint16_t* vtp  = (uint16_t*)p;  p += (size_t)64 * 64 * KPAD_ * 2;
  float*    pbuf = (float*)p;     p += (size_t)4 * PROWS * C_ * 4;
  if ((size_t)(p - (char*)d_ws) > ws_size) return;

  hipMemcpyAsync(xbuf, x_in, (size_t)M_TOK * C_ * sizeof(float),
                 hipMemcpyDeviceToDevice, stream);

  auto cvt = [&](const float* src, uint16_t* dst, size_t n) {
    const int n4 = (int)(n / 4);
    cvt_f32_bf16<<<dim3((n4 + 255) / 256), dim3(256), 0, stream>>>(src, dst, n4);
  };
  cvt(qkv_w,  wq, (size_t)L_ * 3 * C_ * C_);
  cvt(proj_w, wp, (size_t)L_ * C_ * C_);
  cvt(fc1_w,  w1, (size_t)L_ * HID_ * C_);
  cvt(fc2_w,  w2, (size_t)L_ * C_ * HID_);

  // layer-0 ln1 (later layers get it fused into reduce_ln)
  ln_fwd<0><<<dim3(M_TOK), dim3(256), 0, stream>>>(xbuf, ln1_w, ln1_b, hbuf);

  for (int lyr = 0; lyr < L_; ++lyr) {
    // qkv: gemm_s (396 blocks, 2/CU) -> per-head panels
    gemm_s<0, 1><<<dim3(396), dim3(512), 0, stream>>>(
        hbuf, wq + (size_t)lyr * 3 * C_ * C_, qkv_b + (size_t)lyr * 3 * C_,
        nullptr, nullptr, 3 * C_, C_, qp, kp, vtp);
    attn_fwd<<<dim3(64, 17), dim3(256), 0, stream>>>(qp, kp, vtp, hbuf);
    // proj: split2 -> pbuf; fused reduce + residual + ln2 -> hbuf
    gemm_s<3, 2><<<dim3(264), dim3(512), 0, stream>>>(
        hbuf, wp + (size_t)lyr * C_ * C_, nullptr, nullptr, pbuf, C_, C_,
        nullptr, nullptr, nullptr);
    reduce_ln<2, 0><<<dim3(M_TOK), dim3(256), 0, stream>>>(
        pbuf, proj_b + (size_t)lyr * C_, xbuf,
        ln2_w + (size_t)lyr * C_, ln2_b + (size_t)lyr * C_, hbuf);
    // fc1: direct, GELU -> big
    gemm_s<1, 1><<<dim3(528), dim3(512), 0, stream>>>(
        hbuf, w1 + (size_t)lyr * HID_ * C_, fc1_b + (size_t)lyr * HID_,
        big, nullptr, HID_, C_, nullptr, nullptr, nullptr);
    // fc2: split4 -> pbuf; fused reduce + residual + (ln1[next] | final norm)
    gemm_s<3, 4><<<dim3(528), dim3(512), 0, stream>>>(
        big, w2 + (size_t)lyr * C_ * HID_, nullptr, nullptr, pbuf, C_, HID_,
        nullptr, nullptr, nullptr);
    if (lyr < L_ - 1) {
      reduce_ln<4, 0><<<dim3(M_TOK), dim3(256), 0, stream>>>(
          pbuf, fc2_b + (size_t)lyr * C_, xbuf,
          ln1_w + (size_t)(lyr + 1) * C_, ln1_b + (size_t)(lyr + 1) * C_, hbuf);
    } else {
      reduce_ln<4, 1><<<dim3(M_TOK), dim3(256), 0, stream>>>(
          pbuf, fc2_b + (size_t)lyr * C_, xbuf, norm_w, norm_b, d_out);
    }
  }
}

// Round 15
// 2466.004 us; speedup vs baseline: 1.0255x; 1.0021x over previous
//
#include <hip/hip_runtime.h>
#include <cstdint>
#include <cstddef>

#define B_    4
#define N_TOK 1029
#define C_    1024
#define H_    16
#define L_    8
#define HID_  4096
#define M_TOK (B_*N_TOK)   // 4116
#define MP2_  4352
#define PROWS 4224         // pbuf row stride; gemm_s M extent (33*128)
#define KVB_  128
#define KVT2_ 9
#define KPAD_ 1152

typedef float f32x4 __attribute__((ext_vector_type(4)));
typedef short bf16x8 __attribute__((ext_vector_type(8)));

__device__ __forceinline__ uint16_t f2bf(float f) {
  uint32_t u = __float_as_uint(f);
  u += 0x7fffu + ((u >> 16) & 1u);
  return (uint16_t)(u >> 16);
}

__device__ __forceinline__ void async_copy16(const uint16_t* src, uint16_t* lds_dst) {
  __builtin_amdgcn_global_load_lds(
      (const __attribute__((address_space(1))) void*)src,
      (__attribute__((address_space(3))) void*)lds_dst, 16, 0, 0);
}

__device__ __forceinline__ int swz16(int row, int byte_in_row) {
  return row * 128 + (byte_in_row ^ ((row & 7) << 4));
}

// ---------------- fp32 -> bf16 (row-major) ----------------
__global__ __launch_bounds__(256)
void cvt_f32_bf16(const float* __restrict__ in, uint16_t* __restrict__ out, int n4) {
  int i = blockIdx.x * 256 + threadIdx.x;
  if (i < n4) {
    float4 v = reinterpret_cast<const float4*>(in)[i];
    uint64_t pk = (uint64_t)f2bf(v.x) | ((uint64_t)f2bf(v.y) << 16)
                | ((uint64_t)f2bf(v.z) << 32) | ((uint64_t)f2bf(v.w) << 48);
    reinterpret_cast<uint64_t*>(out)[i] = pk;
  }
}

// ---------------- LayerNorm (standalone; layer-0 ln1 only) ----------------
template<int OUTMODE>   // 0: bf16 out
__global__ __launch_bounds__(256)
void ln_fwd(const float* __restrict__ x, const float* __restrict__ w,
            const float* __restrict__ b, void* __restrict__ outp) {
  const int row = blockIdx.x;
  const int tid = threadIdx.x;
  const float4 v = reinterpret_cast<const float4*>(x + (size_t)row * C_)[tid];
  float s  = v.x + v.y + v.z + v.w;
  float s2 = v.x*v.x + v.y*v.y + v.z*v.z + v.w*v.w;
  #pragma unroll
  for (int d = 1; d < 64; d <<= 1) {
    s  += __shfl_xor(s, d);
    s2 += __shfl_xor(s2, d);
  }
  __shared__ float red[8];
  const int wv = tid >> 6;
  if ((tid & 63) == 0) { red[wv] = s; red[wv + 4] = s2; }
  __syncthreads();
  s  = red[0] + red[1] + red[2] + red[3];
  s2 = red[4] + red[5] + red[6] + red[7];
  const float mu = s * (1.0f / C_);
  const float rs = rsqrtf(fmaxf(s2 * (1.0f / C_) - mu * mu, 0.0f) + 1e-6f);
  const float4 wv4 = reinterpret_cast<const float4*>(w)[tid];
  const float4 bv4 = reinterpret_cast<const float4*>(b)[tid];
  const float o0 = (v.x - mu) * rs * wv4.x + bv4.x;
  const float o1 = (v.y - mu) * rs * wv4.y + bv4.y;
  const float o2 = (v.z - mu) * rs * wv4.z + bv4.z;
  const float o3 = (v.w - mu) * rs * wv4.w + bv4.w;
  uint64_t pk = (uint64_t)f2bf(o0) | ((uint64_t)f2bf(o1) << 16)
              | ((uint64_t)f2bf(o2) << 32) | ((uint64_t)f2bf(o3) << 48);
  reinterpret_cast<uint64_t*>((uint16_t*)outp + (size_t)row * C_)[tid] = pk;
}

// ---------------- fused split-K reduce + residual + LayerNorm ----------------
template<int KCH, int OUT>
__global__ __launch_bounds__(256)
void reduce_ln(const float* __restrict__ pbuf, const float* __restrict__ bias,
               float* __restrict__ xbuf, const float* __restrict__ lw,
               const float* __restrict__ lb, void* __restrict__ outp) {
  const int m = blockIdx.x;
  const int c4 = threadIdx.x;
  float4 s = reinterpret_cast<const float4*>(bias)[c4];
  #pragma unroll
  for (int kc = 0; kc < KCH; ++kc) {
    const float4 pv = reinterpret_cast<const float4*>(pbuf + ((size_t)kc * PROWS + m) * C_)[c4];
    s.x += pv.x; s.y += pv.y; s.z += pv.z; s.w += pv.w;
  }
  float4 x = reinterpret_cast<float4*>(xbuf + (size_t)m * C_)[c4];
  x.x += s.x; x.y += s.y; x.z += s.z; x.w += s.w;
  reinterpret_cast<float4*>(xbuf + (size_t)m * C_)[c4] = x;
  float ss  = x.x + x.y + x.z + x.w;
  float ss2 = x.x*x.x + x.y*x.y + x.z*x.z + x.w*x.w;
  #pragma unroll
  for (int d = 1; d < 64; d <<= 1) {
    ss  += __shfl_xor(ss, d);
    ss2 += __shfl_xor(ss2, d);
  }
  __shared__ float red[8];
  const int wv = c4 >> 6;
  if ((c4 & 63) == 0) { red[wv] = ss; red[wv + 4] = ss2; }
  __syncthreads();
  ss  = red[0] + red[1] + red[2] + red[3];
  ss2 = red[4] + red[5] + red[6] + red[7];
  const float mu = ss * (1.0f / C_);
  const float rs = rsqrtf(fmaxf(ss2 * (1.0f / C_) - mu * mu, 0.0f) + 1e-6f);
  const float4 wv4 = reinterpret_cast<const float4*>(lw)[c4];
  const float4 bv4 = reinterpret_cast<const float4*>(lb)[c4];
  const float o0 = (x.x - mu) * rs * wv4.x + bv4.x;
  const float o1 = (x.y - mu) * rs * wv4.y + bv4.y;
  const float o2 = (x.z - mu) * rs * wv4.z + bv4.z;
  const float o3 = (x.w - mu) * rs * wv4.w + bv4.w;
  if (OUT == 0) {
    uint64_t pk = (uint64_t)f2bf(o0) | ((uint64_t)f2bf(o1) << 16)
                | ((uint64_t)f2bf(o2) << 32) | ((uint64_t)f2bf(o3) << 48);
    reinterpret_cast<uint64_t*>((uint16_t*)outp + (size_t)m * C_)[c4] = pk;
  } else {
    float4 o; o.x = o0; o.y = o1; o.z = o2; o.w = o3;
    reinterpret_cast<float4*>((float*)outp + (size_t)m * C_)[c4] = o;
  }
}

// ---------------- epilogue helper ----------------
// EPI 0: qkv head-split. EPI 1: GELU -> bf16 row-major. EPI 3: fp32 partial -> pbuf.
template<int EPI>
__device__ __forceinline__ void epi_store(int m, int col, float v, int Nn, int kc,
    const float* bias, uint16_t* outb, float* pbuf,
    uint16_t* Qp, uint16_t* Kp, uint16_t* VTp) {
  if (EPI == 3) {
    pbuf[((size_t)kc * PROWS + m) * C_ + col] = v;
  } else if (EPI == 1) {
    const float vb = v + bias[col];
    const float u = -1.5957691216f * (vb + 0.044715f * vb * vb * vb);
    const float g = vb * __builtin_amdgcn_rcpf(1.0f + __expf(u));
    outb[(size_t)m * Nn + col] = f2bf(g);
  } else {  // qkv split
    if (m < M_TOK) {
      const float vb = v + bias[col];
      const int which = col >> 10;
      const int h = (col >> 6) & 15;
      const int d = col & 63;
      const int b = m / N_TOK;
      const int key = m - b * N_TOK;
      const int bh = b * 16 + h;
      if (which == 0)      Qp[((size_t)bh * KPAD_ + key) * 64 + d] = f2bf(vb * 0.125f);
      else if (which == 1) Kp[((size_t)bh * KPAD_ + key) * 64 + d] = f2bf(vb);
      else                 VTp[((size_t)bh * 64 + d) * KPAD_ + key] = f2bf(vb);
    }
  }
}

// ---------------- gemm_s: 128x256, BK=64, 8 waves (2Mx4N, wave-tile 64x64) ------
// Single-buffered 48 KB LDS, 2 blocks/CU (launch_bounds(512,4), acc->AGPR).
// T14 reg-staged prefetch: glob->reg(t+1) issued BEFORE compute(t).
template<int EPI, int SPLIT>
__global__ __launch_bounds__(512, 4)
void gemm_s(const uint16_t* __restrict__ A, const uint16_t* __restrict__ W,
            const float* __restrict__ bias, uint16_t* __restrict__ outb,
            float* __restrict__ pbuf, int Nn, int Ktot,
            uint16_t* __restrict__ Qp, uint16_t* __restrict__ Kp,
            uint16_t* __restrict__ VTp) {
  const int nbn = Nn >> 8;
  const int KC = Ktot / SPLIT;
  const int nwg = (int)gridDim.x;
  const int q8 = nwg >> 3, r8 = nwg & 7;
  const int xcd = (int)blockIdx.x & 7, pos = (int)blockIdx.x >> 3;
  const int wgid = (xcd < r8 ? xcd * (q8 + 1) : r8 * (q8 + 1) + (xcd - r8) * q8) + pos;
  const int kc  = wgid / (33 * nbn);
  const int rem = wgid % (33 * nbn);
  const int bm = rem % 33, bn = rem / 33;   // bm fastest: per-XCD blocks share bn

  const int tid = (int)threadIdx.x;
  const int l = tid & 63, w = tid >> 6;
  const int l15 = l & 15, l4 = l >> 4;
  const int wr = w >> 2, wc = w & 3;

  __shared__ char lds[49152];   // A: [0,16K) 128 rows x 128B ; B: [16K,48K) 256 rows

  const uint16_t* Ag = A + (size_t)bm * 128 * Ktot + (size_t)kc * KC;
  const uint16_t* Wg = W + (size_t)bn * 256 * Ktot + (size_t)kc * KC;

  const int srow = tid >> 3;                 // 0..63
  const int schunk = (tid & 7) ^ (srow & 7); // chunk held by slot tid&7
  const int csel0 = ((l4) ^ (l15 & 7)) << 4;
  const int csel1 = ((4 + l4) ^ (l15 & 7)) << 4;

  bf16x8 rA0, rA1, rB0, rB1, rB2, rB3;
  auto gload = [&](int toff) {
    rA0 = *(const bf16x8*)(Ag + (size_t)(srow)      * Ktot + toff + schunk * 8);
    rA1 = *(const bf16x8*)(Ag + (size_t)(64 + srow) * Ktot + toff + schunk * 8);
    rB0 = *(const bf16x8*)(Wg + (size_t)(srow)       * Ktot + toff + schunk * 8);
    rB1 = *(const bf16x8*)(Wg + (size_t)(64 + srow)  * Ktot + toff + schunk * 8);
    rB2 = *(const bf16x8*)(Wg + (size_t)(128 + srow) * Ktot + toff + schunk * 8);
    rB3 = *(const bf16x8*)(Wg + (size_t)(192 + srow) * Ktot + toff + schunk * 8);
  };

  f32x4 acc[4][4] = {};
  const int nt = KC >> 6;
  gload(0);
  for (int t = 0; t < nt; ++t) {
    __syncthreads();   // all reads of LDS (tile t-1) done
    *(bf16x8*)(lds +         tid * 16) = rA0;
    *(bf16x8*)(lds +  8192 + tid * 16) = rA1;
    *(bf16x8*)(lds + 16384 + tid * 16) = rB0;
    *(bf16x8*)(lds + 24576 + tid * 16) = rB1;
    *(bf16x8*)(lds + 32768 + tid * 16) = rB2;
    *(bf16x8*)(lds + 40960 + tid * 16) = rB3;
    __syncthreads();   // writes visible
    if (t + 1 < nt) gload((t + 1) * 64);   // hidden under compute below
    __builtin_amdgcn_sched_barrier(0);
    #pragma unroll
    for (int kk = 0; kk < 2; ++kk) {
      const int cs = kk ? csel1 : csel0;
      bf16x8 afr[4], bfr[4];
      #pragma unroll
      for (int f = 0; f < 4; ++f)
        afr[f] = *(const bf16x8*)(lds + (wr * 64 + f * 16 + l15) * 128 + cs);
      #pragma unroll
      for (int nf = 0; nf < 4; ++nf)
        bfr[nf] = *(const bf16x8*)(lds + 16384 + (wc * 64 + nf * 16 + l15) * 128 + cs);
      #pragma unroll
      for (int f = 0; f < 4; ++f)
        #pragma unroll
        for (int nf = 0; nf < 4; ++nf)
          acc[f][nf] = __builtin_amdgcn_mfma_f32_16x16x32_bf16(afr[f], bfr[nf], acc[f][nf], 0, 0, 0);
    }
  }

  #pragma unroll
  for (int nf = 0; nf < 4; ++nf) {
    const int col = bn * 256 + wc * 64 + nf * 16 + l15;
    #pragma unroll
    for (int mf = 0; mf < 4; ++mf) {
      const int mb = bm * 128 + wr * 64 + mf * 16 + l4 * 4;
      #pragma unroll
      for (int r = 0; r < 4; ++r)
        epi_store<EPI>(mb + r, col, acc[mf][nf][r], Nn, kc, bias, outb, pbuf,
                       Qp, Kp, VTp);
    }
  }
}

// ---------------- Flash attention (swapped operands, q lane-local) ----------------
// LDS 32 KB (P reuses Ksm after QK^T; extra barrier guards the overwrite)
// -> 4 blocks/CU: 1088-block grid fits in ~1.06 rounds (was 1.42 at 3/CU).
__global__ __launch_bounds__(256, 4)
void attn_fwd(const uint16_t* __restrict__ Qp, const uint16_t* __restrict__ Kp,
              const uint16_t* __restrict__ VTp, uint16_t* __restrict__ ob) {
  __shared__ uint16_t Ksm_[KVB_ * 64];   // 16 KB; per-wave 4KB quarter hosts P after QK^T
  __shared__ uint16_t Vsm_[64 * KVB_];   // 16 KB

  const int tid = (int)threadIdx.x;
  const int l = tid & 63, w = tid >> 6;
  const int l15 = l & 15, l4 = l >> 4;
  const int bh = (int)blockIdx.x;
  const int qt = (int)blockIdx.y;

  const uint16_t* Kb = Kp + (size_t)bh * KPAD_ * 64;
  const uint16_t* Vb = VTp + (size_t)bh * 64 * KPAD_;

  bf16x8 qf[2];
  {
    const int qrow = qt * 64 + w * 16 + l15;
    const uint16_t* qbase = Qp + ((size_t)bh * KPAD_ + qrow) * 64;
    qf[0] = *(const bf16x8*)(qbase + l4 * 8);
    qf[1] = *(const bf16x8*)(qbase + 32 + l4 * 8);
  }

  float mrow = -1e30f, lrow = 0.0f;
  f32x4 oacc[4] = {};

  const int krow_s = tid >> 3;
  const int kslot_s = (tid & 7) ^ (krow_s & 7);
  const int vd_s = tid >> 4;
  const int vslot_s = (tid & 15) ^ (vd_s & 15);

  // P region: wave's quarter of Ksm (uint16 units). 16 q-rows x 128 keys (256B rows),
  // 16B-granule XOR swizzle: granule ^= (l15&7), same involution on write & read.
  uint16_t* Pls = Ksm_ + w * 2048;
  const int swz_q = l15 & 7;

  for (int kt = 0; kt < KVT2_; ++kt) {
    const int key0 = kt * KVB_;
    __syncthreads();   // PV reads of previous tile's P (in Ksm) + V done
    #pragma unroll
    for (int it = 0; it < 4; ++it) {
      const int row = it * 32 + krow_s;
      async_copy16(Kb + (size_t)(key0 + row) * 64 + kslot_s * 8,
                   Ksm_ + it * 2048 + tid * 8);
    }
    #pragma unroll
    for (int it = 0; it < 4; ++it) {
      const int d = it * 16 + vd_s;
      async_copy16(Vb + (size_t)d * KPAD_ + key0 + vslot_s * 8,
                   Vsm_ + it * 2048 + tid * 8);
    }
    __syncthreads();   // staged

    f32x4 s[8];
    #pragma unroll
    for (int kf = 0; kf < 8; ++kf) s[kf] = f32x4{0.f, 0.f, 0.f, 0.f};
    #pragma unroll
    for (int kk = 0; kk < 2; ++kk) {
      #pragma unroll
      for (int kf = 0; kf < 8; ++kf) {
        const bf16x8 kfrag = *(const bf16x8*)((const char*)Ksm_ + swz16(kf * 16 + l15, kk * 64 + l4 * 16));
        s[kf] = __builtin_amdgcn_mfma_f32_16x16x32_bf16(kfrag, qf[kk], s[kf], 0, 0, 0);
      }
    }
    __syncthreads();   // ALL waves done reading Ksm -> safe to overwrite with P

    if (kt == KVT2_ - 1) {
      #pragma unroll
      for (int kf = 0; kf < 8; ++kf)
        #pragma unroll
        for (int r = 0; r < 4; ++r)
          if (key0 + kf * 16 + l4 * 4 + r >= N_TOK) s[kf][r] = -1e30f;
    }
    float pmx = s[0][0];
    #pragma unroll
    for (int kf = 0; kf < 8; ++kf)
      #pragma unroll
      for (int r = 0; r < 4; ++r) pmx = fmaxf(pmx, s[kf][r]);
    pmx = fmaxf(pmx, __shfl_xor(pmx, 16));
    pmx = fmaxf(pmx, __shfl_xor(pmx, 32));
    if (!__all(pmx - mrow <= 8.0f)) {
      const float mi = fmaxf(mrow, pmx);
      const float sc = __expf(mrow - mi);
      mrow = mi;
      lrow *= sc;
      #pragma unroll
      for (int df = 0; df < 4; ++df)
        #pragma unroll
        for (int r = 0; r < 4; ++r) oacc[df][r] *= sc;
    }
    float psum = 0.0f;
    #pragma unroll
    for (int kf = 0; kf < 8; ++kf) {
      const float p0 = __expf(s[kf][0] - mrow);
      const float p1 = __expf(s[kf][1] - mrow);
      const float p2 = __expf(s[kf][2] - mrow);
      const float p3 = __expf(s[kf][3] - mrow);
      psum += (p0 + p1) + (p2 + p3);
      const uint64_t pk = (uint64_t)f2bf(p0) | ((uint64_t)f2bf(p1) << 16)
                        | ((uint64_t)f2bf(p2) << 32) | ((uint64_t)f2bf(p3) << 48);
      // logical row-byte kf*32 + l4*8: granule kf*2 + (l4>>1), half (l4&1)
      const int gr = (kf * 2 + (l4 >> 1)) ^ swz_q;
      *(uint64_t*)(Pls + l15 * 128 + gr * 8 + (l4 & 1) * 4) = pk;
    }
    psum += __shfl_xor(psum, 16);
    psum += __shfl_xor(psum, 32);
    lrow += psum;
    #pragma unroll
    for (int kk = 0; kk < 4; ++kk) {
      // logical row-byte kk*64 + l4*16: granule kk*4 + l4
      const bf16x8 pf = *(const bf16x8*)(Pls + l15 * 128 + (((kk * 4 + l4) ^ swz_q) * 8));
      #pragma unroll
      for (int df = 0; df < 4; ++df) {
        const int d = df * 16 + l15;
        const bf16x8 vfrag = *(const bf16x8*)(Vsm_ + d * KVB_ + (((kk * 4 + l4) ^ (d & 15)) * 8));
        oacc[df] = __builtin_amdgcn_mfma_f32_16x16x32_bf16(vfrag, pf, oacc[df], 0, 0, 0);
      }
    }
  }

  const int q = qt * 64 + w * 16 + l15;
  if (q < N_TOK) {
    const float inv = 1.0f / lrow;
    const int m = (bh >> 4) * N_TOK + q;
    const int hbase = (bh & 15) * 64;
    #pragma unroll
    for (int df = 0; df < 4; ++df)
      #pragma unroll
      for (int r = 0; r < 4; ++r) {
        const int c = hbase + df * 16 + l4 * 4 + r;
        ob[(size_t)m * C_ + c] = f2bf(oacc[df][r] * inv);
      }
  }
}

extern "C" void kernel_launch(void* const* d_in, const int* in_sizes, int n_in,
                              void* d_out, int out_size, void* d_ws, size_t ws_size,
                              hipStream_t stream) {
  const float* x_in   = (const float*)d_in[0];
  const float* ln1_w  = (const float*)d_in[1];
  const float* ln1_b  = (const float*)d_in[2];
  const float* qkv_w  = (const float*)d_in[3];
  const float* qkv_b  = (const float*)d_in[4];
  const float* proj_w = (const float*)d_in[5];
  const float* proj_b = (const float*)d_in[6];
  const float* ln2_w  = (const float*)d_in[7];
  const float* ln2_b  = (const float*)d_in[8];
  const float* fc1_w  = (const float*)d_in[9];
  const float* fc1_b  = (const float*)d_in[10];
  const float* fc2_w  = (const float*)d_in[11];
  const float* fc2_b  = (const float*)d_in[12];
  const float* norm_w = (const float*)d_in[13];
  const float* norm_b = (const float*)d_in[14];

  char* p = (char*)d_ws;
  float*    xbuf = (float*)p;     p += (size_t)MP2_ * C_ * 4;
  uint16_t* hbuf = (uint16_t*)p;  p += (size_t)MP2_ * C_ * 2;
  uint16_t* big  = (uint16_t*)p;  p += (size_t)MP2_ * HID_ * 2;
  uint16_t* wq   = (uint16_t*)p;  p += (size_t)L_ * 3 * C_ * C_ * 2;
  uint16_t* wp   = (uint16_t*)p;  p += (size_t)L_ * C_ * C_ * 2;
  uint16_t* w1   = (uint16_t*)p;  p += (size_t)L_ * HID_ * C_ * 2;
  uint16_t* w2   = (uint16_t*)p;  p += (size_t)L_ * C_ * HID_ * 2;
  uint16_t* qp   = (uint16_t*)p;  p += (size_t)64 * KPAD_ * 64 * 2;
  uint16_t* kp   = (uint16_t*)p;  p += (size_t)64 * KPAD_ * 64 * 2;
  uint16_t* vtp  = (uint16_t*)p;  p += (size_t)64 * 64 * KPAD_ * 2;
  float*    pbuf = (float*)p;     p += (size_t)4 * PROWS * C_ * 4;
  if ((size_t)(p - (char*)d_ws) > ws_size) return;

  hipMemcpyAsync(xbuf, x_in, (size_t)M_TOK * C_ * sizeof(float),
                 hipMemcpyDeviceToDevice, stream);

  auto cvt = [&](const float* src, uint16_t* dst, size_t n) {
    const int n4 = (int)(n / 4);
    cvt_f32_bf16<<<dim3((n4 + 255) / 256), dim3(256), 0, stream>>>(src, dst, n4);
  };
  cvt(qkv_w,  wq, (size_t)L_ * 3 * C_ * C_);
  cvt(proj_w, wp, (size_t)L_ * C_ * C_);
  cvt(fc1_w,  w1, (size_t)L_ * HID_ * C_);
  cvt(fc2_w,  w2, (size_t)L_ * C_ * HID_);

  // layer-0 ln1 (later layers get it fused into reduce_ln)
  ln_fwd<0><<<dim3(M_TOK), dim3(256), 0, stream>>>(xbuf, ln1_w, ln1_b, hbuf);

  for (int lyr = 0; lyr < L_; ++lyr) {
    // qkv: gemm_s (396 blocks, 2/CU) -> per-head panels
    gemm_s<0, 1><<<dim3(396), dim3(512), 0, stream>>>(
        hbuf, wq + (size_t)lyr * 3 * C_ * C_, qkv_b + (size_t)lyr * 3 * C_,
        nullptr, nullptr, 3 * C_, C_, qp, kp, vtp);
    attn_fwd<<<dim3(64, 17), dim3(256), 0, stream>>>(qp, kp, vtp, hbuf);
    // proj: split2 -> pbuf; fused reduce + residual + ln2 -> hbuf
    gemm_s<3, 2><<<dim3(264), dim3(512), 0, stream>>>(
        hbuf, wp + (size_t)lyr * C_ * C_, nullptr, nullptr, pbuf, C_, C_,
        nullptr, nullptr, nullptr);
    reduce_ln<2, 0><<<dim3(M_TOK), dim3(256), 0, stream>>>(
        pbuf, proj_b + (size_t)lyr * C_, xbuf,
        ln2_w + (size_t)lyr * C_, ln2_b + (size_t)lyr * C_, hbuf);
    // fc1: direct, GELU -> big
    gemm_s<1, 1><<<dim3(528), dim3(512), 0, stream>>>(
        hbuf, w1 + (size_t)lyr * HID_ * C_, fc1_b + (size_t)lyr * HID_,
        big, nullptr, HID_, C_, nullptr, nullptr, nullptr);
    // fc2: split4 -> pbuf; fused reduce + residual + (ln1[next] | final norm)
    gemm_s<3, 4><<<dim3(528), dim3(512), 0, stream>>>(
        big, w2 + (size_t)lyr * C_ * HID_, nullptr, nullptr, pbuf, C_, HID_,
        nullptr, nullptr, nullptr);
    if (lyr < L_ - 1) {
      reduce_ln<4, 0><<<dim3(M_TOK), dim3(256), 0, stream>>>(
          pbuf, fc2_b + (size_t)lyr * C_, xbuf,
          ln1_w + (size_t)(lyr + 1) * C_, ln1_b + (size_t)(lyr + 1) * C_, hbuf);
    } else {
      reduce_ln<4, 1><<<dim3(M_TOK), dim3(256), 0, stream>>>(
          pbuf, fc2_b + (size_t)lyr * C_, xbuf, norm_w, norm_b, d_out);
    }
  }
}

// Round 16
// 2391.824 us; speedup vs baseline: 1.0573x; 1.0310x over previous
//
#include <hip/hip_runtime.h>
#include <cstdint>
#include <cstddef>

#define B_    4
#define N_TOK 1029
#define C_    1024
#define H_    16
#define L_    8
#define HID_  4096
#define M_TOK (B_*N_TOK)   // 4116
#define MP2_  4352
#define PROWS 4224         // pbuf row stride; gemm_s M extent (33*128)
#define KVB_  128
#define KVT2_ 9            // ceil(1029/128) kv tiles
#define QT2_  9            // ceil(1029/128) q tiles
#define KPAD_ 1152

typedef float f32x4 __attribute__((ext_vector_type(4)));
typedef short bf16x8 __attribute__((ext_vector_type(8)));

__device__ __forceinline__ uint16_t f2bf(float f) {
  uint32_t u = __float_as_uint(f);
  u += 0x7fffu + ((u >> 16) & 1u);
  return (uint16_t)(u >> 16);
}

__device__ __forceinline__ float bf2f(uint16_t h) {
  return __uint_as_float((uint32_t)h << 16);
}

__device__ __forceinline__ void async_copy16(const uint16_t* src, uint16_t* lds_dst) {
  __builtin_amdgcn_global_load_lds(
      (const __attribute__((address_space(1))) void*)src,
      (__attribute__((address_space(3))) void*)lds_dst, 16, 0, 0);
}

__device__ __forceinline__ int swz16(int row, int byte_in_row) {
  return row * 128 + (byte_in_row ^ ((row & 7) << 4));
}

// ---------------- fp32 -> bf16 (row-major) ----------------
__global__ __launch_bounds__(256)
void cvt_f32_bf16(const float* __restrict__ in, uint16_t* __restrict__ out, int n4) {
  int i = blockIdx.x * 256 + threadIdx.x;
  if (i < n4) {
    float4 v = reinterpret_cast<const float4*>(in)[i];
    uint64_t pk = (uint64_t)f2bf(v.x) | ((uint64_t)f2bf(v.y) << 16)
                | ((uint64_t)f2bf(v.z) << 32) | ((uint64_t)f2bf(v.w) << 48);
    reinterpret_cast<uint64_t*>(out)[i] = pk;
  }
}

// ---------------- LayerNorm (standalone; layer-0 ln1 only) ----------------
template<int OUTMODE>   // 0: bf16 out
__global__ __launch_bounds__(256)
void ln_fwd(const float* __restrict__ x, const float* __restrict__ w,
            const float* __restrict__ b, void* __restrict__ outp) {
  const int row = blockIdx.x;
  const int tid = threadIdx.x;
  const float4 v = reinterpret_cast<const float4*>(x + (size_t)row * C_)[tid];
  float s  = v.x + v.y + v.z + v.w;
  float s2 = v.x*v.x + v.y*v.y + v.z*v.z + v.w*v.w;
  #pragma unroll
  for (int d = 1; d < 64; d <<= 1) {
    s  += __shfl_xor(s, d);
    s2 += __shfl_xor(s2, d);
  }
  __shared__ float red[8];
  const int wv = tid >> 6;
  if ((tid & 63) == 0) { red[wv] = s; red[wv + 4] = s2; }
  __syncthreads();
  s  = red[0] + red[1] + red[2] + red[3];
  s2 = red[4] + red[5] + red[6] + red[7];
  const float mu = s * (1.0f / C_);
  const float rs = rsqrtf(fmaxf(s2 * (1.0f / C_) - mu * mu, 0.0f) + 1e-6f);
  const float4 wv4 = reinterpret_cast<const float4*>(w)[tid];
  const float4 bv4 = reinterpret_cast<const float4*>(b)[tid];
  const float o0 = (v.x - mu) * rs * wv4.x + bv4.x;
  const float o1 = (v.y - mu) * rs * wv4.y + bv4.y;
  const float o2 = (v.z - mu) * rs * wv4.z + bv4.z;
  const float o3 = (v.w - mu) * rs * wv4.w + bv4.w;
  uint64_t pk = (uint64_t)f2bf(o0) | ((uint64_t)f2bf(o1) << 16)
              | ((uint64_t)f2bf(o2) << 32) | ((uint64_t)f2bf(o3) << 48);
  reinterpret_cast<uint64_t*>((uint16_t*)outp + (size_t)row * C_)[tid] = pk;
}

// ---------------- fused split-K reduce (bf16 partials) + residual + LayerNorm ----
template<int KCH, int OUT>
__global__ __launch_bounds__(256)
void reduce_ln(const uint16_t* __restrict__ pbuf, const float* __restrict__ bias,
               float* __restrict__ xbuf, const float* __restrict__ lw,
               const float* __restrict__ lb, void* __restrict__ outp) {
  const int m = blockIdx.x;
  const int c4 = threadIdx.x;
  float4 s = reinterpret_cast<const float4*>(bias)[c4];
  #pragma unroll
  for (int kc = 0; kc < KCH; ++kc) {
    const uint64_t pv = *(const uint64_t*)(pbuf + ((size_t)kc * PROWS + m) * C_ + c4 * 4);
    s.x += bf2f((uint16_t)pv);
    s.y += bf2f((uint16_t)(pv >> 16));
    s.z += bf2f((uint16_t)(pv >> 32));
    s.w += bf2f((uint16_t)(pv >> 48));
  }
  float4 x = reinterpret_cast<float4*>(xbuf + (size_t)m * C_)[c4];
  x.x += s.x; x.y += s.y; x.z += s.z; x.w += s.w;
  reinterpret_cast<float4*>(xbuf + (size_t)m * C_)[c4] = x;
  float ss  = x.x + x.y + x.z + x.w;
  float ss2 = x.x*x.x + x.y*x.y + x.z*x.z + x.w*x.w;
  #pragma unroll
  for (int d = 1; d < 64; d <<= 1) {
    ss  += __shfl_xor(ss, d);
    ss2 += __shfl_xor(ss2, d);
  }
  __shared__ float red[8];
  const int wv = c4 >> 6;
  if ((c4 & 63) == 0) { red[wv] = ss; red[wv + 4] = ss2; }
  __syncthreads();
  ss  = red[0] + red[1] + red[2] + red[3];
  ss2 = red[4] + red[5] + red[6] + red[7];
  const float mu = ss * (1.0f / C_);
  const float rs = rsqrtf(fmaxf(ss2 * (1.0f / C_) - mu * mu, 0.0f) + 1e-6f);
  const float4 wv4 = reinterpret_cast<const float4*>(lw)[c4];
  const float4 bv4 = reinterpret_cast<const float4*>(lb)[c4];
  const float o0 = (x.x - mu) * rs * wv4.x + bv4.x;
  const float o1 = (x.y - mu) * rs * wv4.y + bv4.y;
  const float o2 = (x.z - mu) * rs * wv4.z + bv4.z;
  const float o3 = (x.w - mu) * rs * wv4.w + bv4.w;
  if (OUT == 0) {
    uint64_t pk = (uint64_t)f2bf(o0) | ((uint64_t)f2bf(o1) << 16)
                | ((uint64_t)f2bf(o2) << 32) | ((uint64_t)f2bf(o3) << 48);
    reinterpret_cast<uint64_t*>((uint16_t*)outp + (size_t)m * C_)[c4] = pk;
  } else {
    float4 o; o.x = o0; o.y = o1; o.z = o2; o.w = o3;
    reinterpret_cast<float4*>((float*)outp + (size_t)m * C_)[c4] = o;
  }
}

// ---------------- epilogue helper ----------------
// EPI 0: qkv head-split. EPI 1: GELU -> bf16 row-major. EPI 3: bf16 partial -> outb.
template<int EPI>
__device__ __forceinline__ void epi_store(int m, int col, float v, int Nn, int kc,
    const float* bias, uint16_t* outb,
    uint16_t* Qp, uint16_t* Kp, uint16_t* VTp) {
  if (EPI == 3) {
    outb[((size_t)kc * PROWS + m) * C_ + col] = f2bf(v);
  } else if (EPI == 1) {
    const float vb = v + bias[col];
    const float u = -1.5957691216f * (vb + 0.044715f * vb * vb * vb);
    const float g = vb * __builtin_amdgcn_rcpf(1.0f + __expf(u));
    outb[(size_t)m * Nn + col] = f2bf(g);
  } else {  // qkv split
    if (m < M_TOK) {
      const float vb = v + bias[col];
      const int which = col >> 10;
      const int h = (col >> 6) & 15;
      const int d = col & 63;
      const int b = m / N_TOK;
      const int key = m - b * N_TOK;
      const int bh = b * 16 + h;
      if (which == 0)      Qp[((size_t)bh * KPAD_ + key) * 64 + d] = f2bf(vb * 0.125f);
      else if (which == 1) Kp[((size_t)bh * KPAD_ + key) * 64 + d] = f2bf(vb);
      else                 VTp[((size_t)bh * 64 + d) * KPAD_ + key] = f2bf(vb);
    }
  }
}

// ---------------- gemm_s: 128x256, BK=64, 8 waves (2Mx4N, wave-tile 64x64) ------
// Single-buffered 48 KB LDS, 2 blocks/CU (launch_bounds(512,4), acc->AGPR).
// T14 reg-staged prefetch: glob->reg(t+1) issued BEFORE compute(t).
template<int EPI, int SPLIT>
__global__ __launch_bounds__(512, 4)
void gemm_s(const uint16_t* __restrict__ A, const uint16_t* __restrict__ W,
            const float* __restrict__ bias, uint16_t* __restrict__ outb,
            int Nn, int Ktot,
            uint16_t* __restrict__ Qp, uint16_t* __restrict__ Kp,
            uint16_t* __restrict__ VTp) {
  const int nbn = Nn >> 8;
  const int KC = Ktot / SPLIT;
  const int nwg = (int)gridDim.x;
  const int q8 = nwg >> 3, r8 = nwg & 7;
  const int xcd = (int)blockIdx.x & 7, pos = (int)blockIdx.x >> 3;
  const int wgid = (xcd < r8 ? xcd * (q8 + 1) : r8 * (q8 + 1) + (xcd - r8) * q8) + pos;
  const int kc  = wgid / (33 * nbn);
  const int rem = wgid % (33 * nbn);
  const int bm = rem % 33, bn = rem / 33;   // bm fastest: per-XCD blocks share bn

  const int tid = (int)threadIdx.x;
  const int l = tid & 63, w = tid >> 6;
  const int l15 = l & 15, l4 = l >> 4;
  const int wr = w >> 2, wc = w & 3;

  __shared__ char lds[49152];   // A: [0,16K) 128 rows x 128B ; B: [16K,48K) 256 rows

  const uint16_t* Ag = A + (size_t)bm * 128 * Ktot + (size_t)kc * KC;
  const uint16_t* Wg = W + (size_t)bn * 256 * Ktot + (size_t)kc * KC;

  const int srow = tid >> 3;                 // 0..63
  const int schunk = (tid & 7) ^ (srow & 7); // chunk held by slot tid&7
  const int csel0 = ((l4) ^ (l15 & 7)) << 4;
  const int csel1 = ((4 + l4) ^ (l15 & 7)) << 4;

  bf16x8 rA0, rA1, rB0, rB1, rB2, rB3;
  auto gload = [&](int toff) {
    rA0 = *(const bf16x8*)(Ag + (size_t)(srow)      * Ktot + toff + schunk * 8);
    rA1 = *(const bf16x8*)(Ag + (size_t)(64 + srow) * Ktot + toff + schunk * 8);
    rB0 = *(const bf16x8*)(Wg + (size_t)(srow)       * Ktot + toff + schunk * 8);
    rB1 = *(const bf16x8*)(Wg + (size_t)(64 + srow)  * Ktot + toff + schunk * 8);
    rB2 = *(const bf16x8*)(Wg + (size_t)(128 + srow) * Ktot + toff + schunk * 8);
    rB3 = *(const bf16x8*)(Wg + (size_t)(192 + srow) * Ktot + toff + schunk * 8);
  };

  f32x4 acc[4][4] = {};
  const int nt = KC >> 6;
  gload(0);
  for (int t = 0; t < nt; ++t) {
    __syncthreads();   // all reads of LDS (tile t-1) done
    *(bf16x8*)(lds +         tid * 16) = rA0;
    *(bf16x8*)(lds +  8192 + tid * 16) = rA1;
    *(bf16x8*)(lds + 16384 + tid * 16) = rB0;
    *(bf16x8*)(lds + 24576 + tid * 16) = rB1;
    *(bf16x8*)(lds + 32768 + tid * 16) = rB2;
    *(bf16x8*)(lds + 40960 + tid * 16) = rB3;
    __syncthreads();   // writes visible
    if (t + 1 < nt) gload((t + 1) * 64);   // hidden under compute below
    __builtin_amdgcn_sched_barrier(0);
    #pragma unroll
    for (int kk = 0; kk < 2; ++kk) {
      const int cs = kk ? csel1 : csel0;
      bf16x8 afr[4], bfr[4];
      #pragma unroll
      for (int f = 0; f < 4; ++f)
        afr[f] = *(const bf16x8*)(lds + (wr * 64 + f * 16 + l15) * 128 + cs);
      #pragma unroll
      for (int nf = 0; nf < 4; ++nf)
        bfr[nf] = *(const bf16x8*)(lds + 16384 + (wc * 64 + nf * 16 + l15) * 128 + cs);
      #pragma unroll
      for (int f = 0; f < 4; ++f)
        #pragma unroll
        for (int nf = 0; nf < 4; ++nf)
          acc[f][nf] = __builtin_amdgcn_mfma_f32_16x16x32_bf16(afr[f], bfr[nf], acc[f][nf], 0, 0, 0);
    }
  }

  #pragma unroll
  for (int nf = 0; nf < 4; ++nf) {
    const int col = bn * 256 + wc * 64 + nf * 16 + l15;
    #pragma unroll
    for (int mf = 0; mf < 4; ++mf) {
      const int mb = bm * 128 + wr * 64 + mf * 16 + l4 * 4;
      #pragma unroll
      for (int r = 0; r < 4; ++r)
        epi_store<EPI>(mb + r, col, acc[mf][nf][r], Nn, kc, bias, outb,
                       Qp, Kp, VTp);
    }
  }
}

// ---------------- Flash attention: 128-q-row blocks, 8 waves x 16 q ----------------
// Halves K/V re-staging vs 64-q blocks. LDS 64 KB -> 2 blocks/CU (16 waves/CU).
__global__ __launch_bounds__(512, 4)
void attn_fwd(const uint16_t* __restrict__ Qp, const uint16_t* __restrict__ Kp,
              const uint16_t* __restrict__ VTp, uint16_t* __restrict__ ob) {
  __shared__ uint16_t Ksm_[KVB_ * 64];     // 16 KB [key 128][d 64], chunk-XOR slots
  __shared__ uint16_t Vsm_[64 * KVB_];     // 16 KB [d 64][key 128], granule-XOR slots
  __shared__ uint16_t Psm_[8][16 * 128];   // 32 KB per-wave P (granule swizzle)

  const int tid = (int)threadIdx.x;
  const int l = tid & 63, w = tid >> 6;    // w = 0..7
  const int l15 = l & 15, l4 = l >> 4;
  const int bh = (int)blockIdx.x;
  const int qt = (int)blockIdx.y;

  const uint16_t* Kb = Kp + (size_t)bh * KPAD_ * 64;
  const uint16_t* Vb = VTp + (size_t)bh * 64 * KPAD_;

  bf16x8 qf[2];
  {
    const int qrow = qt * 128 + w * 16 + l15;
    const uint16_t* qbase = Qp + ((size_t)bh * KPAD_ + qrow) * 64;
    qf[0] = *(const bf16x8*)(qbase + l4 * 8);
    qf[1] = *(const bf16x8*)(qbase + 32 + l4 * 8);
  }

  float mrow = -1e30f, lrow = 0.0f;
  f32x4 oacc[4] = {};

  // staging lanes (512 threads): K rows 128B (8 thr/row), V rows 256B (16 thr/row)
  const int krow_s = tid >> 3;             // 0..63
  const int kslot_s = tid & 7;
  const int vd_s = tid >> 4;               // 0..31
  const int vslot_s = tid & 15;

  uint16_t* Pls = &Psm_[w][0];
  const int swz_q = l15 & 7;

  for (int kt = 0; kt < KVT2_; ++kt) {
    const int key0 = kt * KVB_;
    __syncthreads();   // all reads of previous K/V/P done
    #pragma unroll
    for (int it = 0; it < 2; ++it) {
      const int row = it * 64 + krow_s;
      async_copy16(Kb + (size_t)(key0 + row) * 64 + (kslot_s ^ (row & 7)) * 8,
                   Ksm_ + it * 4096 + tid * 8);
    }
    #pragma unroll
    for (int it = 0; it < 2; ++it) {
      const int d = it * 32 + vd_s;
      async_copy16(Vb + (size_t)d * KPAD_ + key0 + (vslot_s ^ (d & 15)) * 8,
                   Vsm_ + it * 4096 + tid * 8);
    }
    __syncthreads();   // staged

    f32x4 s[8];
    #pragma unroll
    for (int kf = 0; kf < 8; ++kf) s[kf] = f32x4{0.f, 0.f, 0.f, 0.f};
    #pragma unroll
    for (int kk = 0; kk < 2; ++kk) {
      #pragma unroll
      for (int kf = 0; kf < 8; ++kf) {
        const bf16x8 kfrag = *(const bf16x8*)((const char*)Ksm_ + swz16(kf * 16 + l15, kk * 64 + l4 * 16));
        s[kf] = __builtin_amdgcn_mfma_f32_16x16x32_bf16(kfrag, qf[kk], s[kf], 0, 0, 0);
      }
    }
    if (kt == KVT2_ - 1) {
      #pragma unroll
      for (int kf = 0; kf < 8; ++kf)
        #pragma unroll
        for (int r = 0; r < 4; ++r)
          if (key0 + kf * 16 + l4 * 4 + r >= N_TOK) s[kf][r] = -1e30f;
    }
    float pmx = s[0][0];
    #pragma unroll
    for (int kf = 0; kf < 8; ++kf)
      #pragma unroll
      for (int r = 0; r < 4; ++r) pmx = fmaxf(pmx, s[kf][r]);
    pmx = fmaxf(pmx, __shfl_xor(pmx, 16));
    pmx = fmaxf(pmx, __shfl_xor(pmx, 32));
    if (!__all(pmx - mrow <= 8.0f)) {
      const float mi = fmaxf(mrow, pmx);
      const float sc = __expf(mrow - mi);
      mrow = mi;
      lrow *= sc;
      #pragma unroll
      for (int df = 0; df < 4; ++df)
        #pragma unroll
        for (int r = 0; r < 4; ++r) oacc[df][r] *= sc;
    }
    float psum = 0.0f;
    #pragma unroll
    for (int kf = 0; kf < 8; ++kf) {
      const float p0 = __expf(s[kf][0] - mrow);
      const float p1 = __expf(s[kf][1] - mrow);
      const float p2 = __expf(s[kf][2] - mrow);
      const float p3 = __expf(s[kf][3] - mrow);
      psum += (p0 + p1) + (p2 + p3);
      const uint64_t pk = (uint64_t)f2bf(p0) | ((uint64_t)f2bf(p1) << 16)
                        | ((uint64_t)f2bf(p2) << 32) | ((uint64_t)f2bf(p3) << 48);
      const int gr = (kf * 2 + (l4 >> 1)) ^ swz_q;
      *(uint64_t*)(Pls + l15 * 128 + gr * 8 + (l4 & 1) * 4) = pk;
    }
    psum += __shfl_xor(psum, 16);
    psum += __shfl_xor(psum, 32);
    lrow += psum;
    #pragma unroll
    for (int kk = 0; kk < 4; ++kk) {
      const bf16x8 pf = *(const bf16x8*)(Pls + l15 * 128 + (((kk * 4 + l4) ^ swz_q) * 8));
      #pragma unroll
      for (int df = 0; df < 4; ++df) {
        const int d = df * 16 + l15;
        const bf16x8 vfrag = *(const bf16x8*)(Vsm_ + d * KVB_ + (((kk * 4 + l4) ^ (d & 15)) * 8));
        oacc[df] = __builtin_amdgcn_mfma_f32_16x16x32_bf16(vfrag, pf, oacc[df], 0, 0, 0);
      }
    }
  }

  const int q = qt * 128 + w * 16 + l15;
  if (q < N_TOK) {
    const float inv = 1.0f / lrow;
    const int m = (bh >> 4) * N_TOK + q;
    const int hbase = (bh & 15) * 64;
    #pragma unroll
    for (int df = 0; df < 4; ++df)
      #pragma unroll
      for (int r = 0; r < 4; ++r) {
        const int c = hbase + df * 16 + l4 * 4 + r;
        ob[(size_t)m * C_ + c] = f2bf(oacc[df][r] * inv);
      }
  }
}

extern "C" void kernel_launch(void* const* d_in, const int* in_sizes, int n_in,
                              void* d_out, int out_size, void* d_ws, size_t ws_size,
                              hipStream_t stream) {
  const float* x_in   = (const float*)d_in[0];
  const float* ln1_w  = (const float*)d_in[1];
  const float* ln1_b  = (const float*)d_in[2];
  const float* qkv_w  = (const float*)d_in[3];
  const float* qkv_b  = (const float*)d_in[4];
  const float* proj_w = (const float*)d_in[5];
  const float* proj_b = (const float*)d_in[6];
  const float* ln2_w  = (const float*)d_in[7];
  const float* ln2_b  = (const float*)d_in[8];
  const float* fc1_w  = (const float*)d_in[9];
  const float* fc1_b  = (const float*)d_in[10];
  const float* fc2_w  = (const float*)d_in[11];
  const float* fc2_b  = (const float*)d_in[12];
  const float* norm_w = (const float*)d_in[13];
  const float* norm_b = (const float*)d_in[14];

  char* p = (char*)d_ws;
  float*    xbuf = (float*)p;     p += (size_t)MP2_ * C_ * 4;
  uint16_t* hbuf = (uint16_t*)p;  p += (size_t)MP2_ * C_ * 2;
  uint16_t* big  = (uint16_t*)p;  p += (size_t)MP2_ * HID_ * 2;
  uint16_t* wq   = (uint16_t*)p;  p += (size_t)L_ * 3 * C_ * C_ * 2;
  uint16_t* wp   = (uint16_t*)p;  p += (size_t)L_ * C_ * C_ * 2;
  uint16_t* w1   = (uint16_t*)p;  p += (size_t)L_ * HID_ * C_ * 2;
  uint16_t* w2   = (uint16_t*)p;  p += (size_t)L_ * C_ * HID_ * 2;
  uint16_t* qp   = (uint16_t*)p;  p += (size_t)64 * KPAD_ * 64 * 2;
  uint16_t* kp   = (uint16_t*)p;  p += (size_t)64 * KPAD_ * 64 * 2;
  uint16_t* vtp  = (uint16_t*)p;  p += (size_t)64 * 64 * KPAD_ * 2;
  uint16_t* pbuf = (uint16_t*)p;  p += (size_t)4 * PROWS * C_ * 2;  // bf16 partials
  if ((size_t)(p - (char*)d_ws) > ws_size) return;

  hipMemcpyAsync(xbuf, x_in, (size_t)M_TOK * C_ * sizeof(float),
                 hipMemcpyDeviceToDevice, stream);

  auto cvt = [&](const float* src, uint16_t* dst, size_t n) {
    const int n4 = (int)(n / 4);
    cvt_f32_bf16<<<dim3((n4 + 255) / 256), dim3(256), 0, stream>>>(src, dst, n4);
  };
  cvt(qkv_w,  wq, (size_t)L_ * 3 * C_ * C_);
  cvt(proj_w, wp, (size_t)L_ * C_ * C_);
  cvt(fc1_w,  w1, (size_t)L_ * HID_ * C_);
  cvt(fc2_w,  w2, (size_t)L_ * C_ * HID_);

  // layer-0 ln1 (later layers get it fused into reduce_ln)
  ln_fwd<0><<<dim3(M_TOK), dim3(256), 0, stream>>>(xbuf, ln1_w, ln1_b, hbuf);

  for (int lyr = 0; lyr < L_; ++lyr) {
    // qkv: gemm_s (396 blocks, 2/CU) -> per-head panels
    gemm_s<0, 1><<<dim3(396), dim3(512), 0, stream>>>(
        hbuf, wq + (size_t)lyr * 3 * C_ * C_, qkv_b + (size_t)lyr * 3 * C_,
        nullptr, 3 * C_, C_, qp, kp, vtp);
    attn_fwd<<<dim3(64, QT2_), dim3(512), 0, stream>>>(qp, kp, vtp, hbuf);
    // proj: split2 -> bf16 partials; fused reduce + residual + ln2 -> hbuf
    gemm_s<3, 2><<<dim3(264), dim3(512), 0, stream>>>(
        hbuf, wp + (size_t)lyr * C_ * C_, nullptr, pbuf, C_, C_,
        nullptr, nullptr, nullptr);
    reduce_ln<2, 0><<<dim3(M_TOK), dim3(256), 0, stream>>>(
        pbuf, proj_b + (size_t)lyr * C_, xbuf,
        ln2_w + (size_t)lyr * C_, ln2_b + (size_t)lyr * C_, hbuf);
    // fc1: direct, GELU -> big
    gemm_s<1, 1><<<dim3(528), dim3(512), 0, stream>>>(
        hbuf, w1 + (size_t)lyr * HID_ * C_, fc1_b + (size_t)lyr * HID_,
        big, HID_, C_, nullptr, nullptr, nullptr);
    // fc2: split4 -> bf16 partials; fused reduce + (ln1[next] | final norm)
    gemm_s<3, 4><<<dim3(528), dim3(512), 0, stream>>>(
        big, w2 + (size_t)lyr * C_ * HID_, nullptr, pbuf, C_, HID_,
        nullptr, nullptr, nullptr);
    if (lyr < L_ - 1) {
      reduce_ln<4, 0><<<dim3(M_TOK), dim3(256), 0, stream>>>(
          pbuf, fc2_b + (size_t)lyr * C_, xbuf,
          ln1_w + (size_t)(lyr + 1) * C_, ln1_b + (size_t)(lyr + 1) * C_, hbuf);
    } else {
      reduce_ln<4, 1><<<dim3(M_TOK), dim3(256), 0, stream>>>(
          pbuf, fc2_b + (size_t)lyr * C_, xbuf, norm_w, norm_b, d_out);
    }
  }
}

// Round 17
// 2299.764 us; speedup vs baseline: 1.0996x; 1.0400x over previous
//
#include <hip/hip_runtime.h>
#include <cstdint>
#include <cstddef>

#define B_    4
#define N_TOK 1029
#define C_    1024
#define H_    16
#define L_    8
#define HID_  4096
#define M_TOK (B_*N_TOK)   // 4116
#define MP2_  4352
#define PROWS 4224         // pbuf row stride; gemm_s M extent (33*128)
#define KVB_  128
#define KVT2_ 9            // ceil(1029/128) kv tiles
#define QT2_  9            // ceil(1029/128) q tiles
#define KPAD_ 1152

typedef float f32x4 __attribute__((ext_vector_type(4)));
typedef short bf16x8 __attribute__((ext_vector_type(8)));

__device__ __forceinline__ uint16_t f2bf(float f) {
  uint32_t u = __float_as_uint(f);
  u += 0x7fffu + ((u >> 16) & 1u);
  return (uint16_t)(u >> 16);
}

__device__ __forceinline__ float bf2f(uint16_t h) {
  return __uint_as_float((uint32_t)h << 16);
}

__device__ __forceinline__ void async_copy16(const uint16_t* src, uint16_t* lds_dst) {
  __builtin_amdgcn_global_load_lds(
      (const __attribute__((address_space(1))) void*)src,
      (__attribute__((address_space(3))) void*)lds_dst, 16, 0, 0);
}

__device__ __forceinline__ int swz16(int row, int byte_in_row) {
  return row * 128 + (byte_in_row ^ ((row & 7) << 4));
}

// ---------------- fp32 -> bf16 (row-major) ----------------
__global__ __launch_bounds__(256)
void cvt_f32_bf16(const float* __restrict__ in, uint16_t* __restrict__ out, int n4) {
  int i = blockIdx.x * 256 + threadIdx.x;
  if (i < n4) {
    float4 v = reinterpret_cast<const float4*>(in)[i];
    uint64_t pk = (uint64_t)f2bf(v.x) | ((uint64_t)f2bf(v.y) << 16)
                | ((uint64_t)f2bf(v.z) << 32) | ((uint64_t)f2bf(v.w) << 48);
    reinterpret_cast<uint64_t*>(out)[i] = pk;
  }
}

// ---------------- LayerNorm (standalone; layer-0 ln1 only) ----------------
template<int OUTMODE>   // 0: bf16 out
__global__ __launch_bounds__(256)
void ln_fwd(const float* __restrict__ x, const float* __restrict__ w,
            const float* __restrict__ b, void* __restrict__ outp) {
  const int row = blockIdx.x;
  const int tid = threadIdx.x;
  const float4 v = reinterpret_cast<const float4*>(x + (size_t)row * C_)[tid];
  float s  = v.x + v.y + v.z + v.w;
  float s2 = v.x*v.x + v.y*v.y + v.z*v.z + v.w*v.w;
  #pragma unroll
  for (int d = 1; d < 64; d <<= 1) {
    s  += __shfl_xor(s, d);
    s2 += __shfl_xor(s2, d);
  }
  __shared__ float red[8];
  const int wv = tid >> 6;
  if ((tid & 63) == 0) { red[wv] = s; red[wv + 4] = s2; }
  __syncthreads();
  s  = red[0] + red[1] + red[2] + red[3];
  s2 = red[4] + red[5] + red[6] + red[7];
  const float mu = s * (1.0f / C_);
  const float rs = rsqrtf(fmaxf(s2 * (1.0f / C_) - mu * mu, 0.0f) + 1e-6f);
  const float4 wv4 = reinterpret_cast<const float4*>(w)[tid];
  const float4 bv4 = reinterpret_cast<const float4*>(b)[tid];
  const float o0 = (v.x - mu) * rs * wv4.x + bv4.x;
  const float o1 = (v.y - mu) * rs * wv4.y + bv4.y;
  const float o2 = (v.z - mu) * rs * wv4.z + bv4.z;
  const float o3 = (v.w - mu) * rs * wv4.w + bv4.w;
  uint64_t pk = (uint64_t)f2bf(o0) | ((uint64_t)f2bf(o1) << 16)
              | ((uint64_t)f2bf(o2) << 32) | ((uint64_t)f2bf(o3) << 48);
  reinterpret_cast<uint64_t*>((uint16_t*)outp + (size_t)row * C_)[tid] = pk;
}

// ---------------- fused split-K reduce (bf16 partials) + residual + LayerNorm ----
template<int KCH, int OUT>
__global__ __launch_bounds__(256)
void reduce_ln(const uint16_t* __restrict__ pbuf, const float* __restrict__ bias,
               float* __restrict__ xbuf, const float* __restrict__ lw,
               const float* __restrict__ lb, void* __restrict__ outp) {
  const int m = blockIdx.x;
  const int c4 = threadIdx.x;
  float4 s = reinterpret_cast<const float4*>(bias)[c4];
  #pragma unroll
  for (int kc = 0; kc < KCH; ++kc) {
    const uint64_t pv = *(const uint64_t*)(pbuf + ((size_t)kc * PROWS + m) * C_ + c4 * 4);
    s.x += bf2f((uint16_t)pv);
    s.y += bf2f((uint16_t)(pv >> 16));
    s.z += bf2f((uint16_t)(pv >> 32));
    s.w += bf2f((uint16_t)(pv >> 48));
  }
  float4 x = reinterpret_cast<float4*>(xbuf + (size_t)m * C_)[c4];
  x.x += s.x; x.y += s.y; x.z += s.z; x.w += s.w;
  reinterpret_cast<float4*>(xbuf + (size_t)m * C_)[c4] = x;
  float ss  = x.x + x.y + x.z + x.w;
  float ss2 = x.x*x.x + x.y*x.y + x.z*x.z + x.w*x.w;
  #pragma unroll
  for (int d = 1; d < 64; d <<= 1) {
    ss  += __shfl_xor(ss, d);
    ss2 += __shfl_xor(ss2, d);
  }
  __shared__ float red[8];
  const int wv = c4 >> 6;
  if ((c4 & 63) == 0) { red[wv] = ss; red[wv + 4] = ss2; }
  __syncthreads();
  ss  = red[0] + red[1] + red[2] + red[3];
  ss2 = red[4] + red[5] + red[6] + red[7];
  const float mu = ss * (1.0f / C_);
  const float rs = rsqrtf(fmaxf(ss2 * (1.0f / C_) - mu * mu, 0.0f) + 1e-6f);
  const float4 wv4 = reinterpret_cast<const float4*>(lw)[c4];
  const float4 bv4 = reinterpret_cast<const float4*>(lb)[c4];
  const float o0 = (x.x - mu) * rs * wv4.x + bv4.x;
  const float o1 = (x.y - mu) * rs * wv4.y + bv4.y;
  const float o2 = (x.z - mu) * rs * wv4.z + bv4.z;
  const float o3 = (x.w - mu) * rs * wv4.w + bv4.w;
  if (OUT == 0) {
    uint64_t pk = (uint64_t)f2bf(o0) | ((uint64_t)f2bf(o1) << 16)
                | ((uint64_t)f2bf(o2) << 32) | ((uint64_t)f2bf(o3) << 48);
    reinterpret_cast<uint64_t*>((uint16_t*)outp + (size_t)m * C_)[c4] = pk;
  } else {
    float4 o; o.x = o0; o.y = o1; o.z = o2; o.w = o3;
    reinterpret_cast<float4*>((float*)outp + (size_t)m * C_)[c4] = o;
  }
}

// ---------------- epilogue helper ----------------
// EPI 0: qkv head-split. EPI 1: GELU -> bf16 row-major. EPI 3: bf16 partial -> outb.
template<int EPI>
__device__ __forceinline__ void epi_store(int m, int col, float v, int Nn, int kc,
    const float* bias, uint16_t* outb,
    uint16_t* Qp, uint16_t* Kp, uint16_t* VTp) {
  if (EPI == 3) {
    outb[((size_t)kc * PROWS + m) * C_ + col] = f2bf(v);
  } else if (EPI == 1) {
    const float vb = v + bias[col];
    const float u = -1.5957691216f * (vb + 0.044715f * vb * vb * vb);
    const float g = vb * __builtin_amdgcn_rcpf(1.0f + __expf(u));
    outb[(size_t)m * Nn + col] = f2bf(g);
  } else {  // qkv split
    if (m < M_TOK) {
      const float vb = v + bias[col];
      const int which = col >> 10;
      const int h = (col >> 6) & 15;
      const int d = col & 63;
      const int b = m / N_TOK;
      const int key = m - b * N_TOK;
      const int bh = b * 16 + h;
      if (which == 0)      Qp[((size_t)bh * KPAD_ + key) * 64 + d] = f2bf(vb * 0.125f);
      else if (which == 1) Kp[((size_t)bh * KPAD_ + key) * 64 + d] = f2bf(vb);
      else                 VTp[((size_t)bh * 64 + d) * KPAD_ + key] = f2bf(vb);
    }
  }
}

// ---------------- gemm_s: 128x256, BK=64, 8 waves (2Mx4N, wave-tile 64x64) ------
// Single-buffered 48 KB LDS, 2 blocks/CU (launch_bounds(512,4), acc->AGPR).
// T14 reg-staged prefetch: glob->reg(t+1) issued BEFORE compute(t).
// 2-D supertile decode (11 bm x 4 bn, stn-fastest): per-XCD concurrent working set
// ~= 11 A panels (2.75 MB) + ~6 B panels (3 MB) ~ L2-sized -> staged reads L2-hit.
template<int EPI, int SPLIT>
__global__ __launch_bounds__(512, 4)
void gemm_s(const uint16_t* __restrict__ A, const uint16_t* __restrict__ W,
            const float* __restrict__ bias, uint16_t* __restrict__ outb,
            int Nn, int Ktot,
            uint16_t* __restrict__ Qp, uint16_t* __restrict__ Kp,
            uint16_t* __restrict__ VTp) {
  const int nbn = Nn >> 8;
  const int KC = Ktot / SPLIT;
  const int nwg = (int)gridDim.x;
  const int q8 = nwg >> 3, r8 = nwg & 7;
  const int xcd = (int)blockIdx.x & 7, pos = (int)blockIdx.x >> 3;
  const int wgid = (xcd < r8 ? xcd * (q8 + 1) : r8 * (q8 + 1) + (xcd - r8) * q8) + pos;
  const int kc  = wgid / (33 * nbn);
  const int rem = wgid % (33 * nbn);
  // supertile 11bm x 4bn; stn-fastest so consecutive supertiles share A panels
  const int stn_count = nbn >> 2;
  const int st = rem / 44, w44 = rem % 44;
  const int stm = st / stn_count, stn = st % stn_count;
  const int bm = stm * 11 + (w44 % 11);
  const int bn = stn * 4 + (w44 / 11);

  const int tid = (int)threadIdx.x;
  const int l = tid & 63, w = tid >> 6;
  const int l15 = l & 15, l4 = l >> 4;
  const int wr = w >> 2, wc = w & 3;

  __shared__ char lds[49152];   // A: [0,16K) 128 rows x 128B ; B: [16K,48K) 256 rows

  const uint16_t* Ag = A + (size_t)bm * 128 * Ktot + (size_t)kc * KC;
  const uint16_t* Wg = W + (size_t)bn * 256 * Ktot + (size_t)kc * KC;

  const int srow = tid >> 3;                 // 0..63
  const int schunk = (tid & 7) ^ (srow & 7); // chunk held by slot tid&7
  const int csel0 = ((l4) ^ (l15 & 7)) << 4;
  const int csel1 = ((4 + l4) ^ (l15 & 7)) << 4;

  bf16x8 rA0, rA1, rB0, rB1, rB2, rB3;
  auto gload = [&](int toff) {
    rA0 = *(const bf16x8*)(Ag + (size_t)(srow)      * Ktot + toff + schunk * 8);
    rA1 = *(const bf16x8*)(Ag + (size_t)(64 + srow) * Ktot + toff + schunk * 8);
    rB0 = *(const bf16x8*)(Wg + (size_t)(srow)       * Ktot + toff + schunk * 8);
    rB1 = *(const bf16x8*)(Wg + (size_t)(64 + srow)  * Ktot + toff + schunk * 8);
    rB2 = *(const bf16x8*)(Wg + (size_t)(128 + srow) * Ktot + toff + schunk * 8);
    rB3 = *(const bf16x8*)(Wg + (size_t)(192 + srow) * Ktot + toff + schunk * 8);
  };

  f32x4 acc[4][4] = {};
  const int nt = KC >> 6;
  gload(0);
  for (int t = 0; t < nt; ++t) {
    __syncthreads();   // all reads of LDS (tile t-1) done
    *(bf16x8*)(lds +         tid * 16) = rA0;
    *(bf16x8*)(lds +  8192 + tid * 16) = rA1;
    *(bf16x8*)(lds + 16384 + tid * 16) = rB0;
    *(bf16x8*)(lds + 24576 + tid * 16) = rB1;
    *(bf16x8*)(lds + 32768 + tid * 16) = rB2;
    *(bf16x8*)(lds + 40960 + tid * 16) = rB3;
    __syncthreads();   // writes visible
    if (t + 1 < nt) gload((t + 1) * 64);   // hidden under compute below
    __builtin_amdgcn_sched_barrier(0);
    #pragma unroll
    for (int kk = 0; kk < 2; ++kk) {
      const int cs = kk ? csel1 : csel0;
      bf16x8 afr[4], bfr[4];
      #pragma unroll
      for (int f = 0; f < 4; ++f)
        afr[f] = *(const bf16x8*)(lds + (wr * 64 + f * 16 + l15) * 128 + cs);
      #pragma unroll
      for (int nf = 0; nf < 4; ++nf)
        bfr[nf] = *(const bf16x8*)(lds + 16384 + (wc * 64 + nf * 16 + l15) * 128 + cs);
      #pragma unroll
      for (int f = 0; f < 4; ++f)
        #pragma unroll
        for (int nf = 0; nf < 4; ++nf)
          acc[f][nf] = __builtin_amdgcn_mfma_f32_16x16x32_bf16(afr[f], bfr[nf], acc[f][nf], 0, 0, 0);
    }
  }

  #pragma unroll
  for (int nf = 0; nf < 4; ++nf) {
    const int col = bn * 256 + wc * 64 + nf * 16 + l15;
    #pragma unroll
    for (int mf = 0; mf < 4; ++mf) {
      const int mb = bm * 128 + wr * 64 + mf * 16 + l4 * 4;
      #pragma unroll
      for (int r = 0; r < 4; ++r)
        epi_store<EPI>(mb + r, col, acc[mf][nf][r], Nn, kc, bias, outb,
                       Qp, Kp, VTp);
    }
  }
}

// ---------------- Flash attention: 128-q-row blocks, 8 waves x 16 q ----------------
__global__ __launch_bounds__(512, 4)
void attn_fwd(const uint16_t* __restrict__ Qp, const uint16_t* __restrict__ Kp,
              const uint16_t* __restrict__ VTp, uint16_t* __restrict__ ob) {
  __shared__ uint16_t Ksm_[KVB_ * 64];     // 16 KB [key 128][d 64], chunk-XOR slots
  __shared__ uint16_t Vsm_[64 * KVB_];     // 16 KB [d 64][key 128], granule-XOR slots
  __shared__ uint16_t Psm_[8][16 * 128];   // 32 KB per-wave P (granule swizzle)

  const int tid = (int)threadIdx.x;
  const int l = tid & 63, w = tid >> 6;    // w = 0..7
  const int l15 = l & 15, l4 = l >> 4;
  const int bh = (int)blockIdx.x;
  const int qt = (int)blockIdx.y;

  const uint16_t* Kb = Kp + (size_t)bh * KPAD_ * 64;
  const uint16_t* Vb = VTp + (size_t)bh * 64 * KPAD_;

  bf16x8 qf[2];
  {
    const int qrow = qt * 128 + w * 16 + l15;
    const uint16_t* qbase = Qp + ((size_t)bh * KPAD_ + qrow) * 64;
    qf[0] = *(const bf16x8*)(qbase + l4 * 8);
    qf[1] = *(const bf16x8*)(qbase + 32 + l4 * 8);
  }

  float mrow = -1e30f, lrow = 0.0f;
  f32x4 oacc[4] = {};

  const int krow_s = tid >> 3;             // 0..63
  const int kslot_s = tid & 7;
  const int vd_s = tid >> 4;               // 0..31
  const int vslot_s = tid & 15;

  uint16_t* Pls = &Psm_[w][0];
  const int swz_q = l15 & 7;

  for (int kt = 0; kt < KVT2_; ++kt) {
    const int key0 = kt * KVB_;
    __syncthreads();   // all reads of previous K/V/P done
    #pragma unroll
    for (int it = 0; it < 2; ++it) {
      const int row = it * 64 + krow_s;
      async_copy16(Kb + (size_t)(key0 + row) * 64 + (kslot_s ^ (row & 7)) * 8,
                   Ksm_ + it * 4096 + tid * 8);
    }
    #pragma unroll
    for (int it = 0; it < 2; ++it) {
      const int d = it * 32 + vd_s;
      async_copy16(Vb + (size_t)d * KPAD_ + key0 + (vslot_s ^ (d & 15)) * 8,
                   Vsm_ + it * 4096 + tid * 8);
    }
    __syncthreads();   // staged

    f32x4 s[8];
    #pragma unroll
    for (int kf = 0; kf < 8; ++kf) s[kf] = f32x4{0.f, 0.f, 0.f, 0.f};
    #pragma unroll
    for (int kk = 0; kk < 2; ++kk) {
      #pragma unroll
      for (int kf = 0; kf < 8; ++kf) {
        const bf16x8 kfrag = *(const bf16x8*)((const char*)Ksm_ + swz16(kf * 16 + l15, kk * 64 + l4 * 16));
        s[kf] = __builtin_amdgcn_mfma_f32_16x16x32_bf16(kfrag, qf[kk], s[kf], 0, 0, 0);
      }
    }
    if (kt == KVT2_ - 1) {
      #pragma unroll
      for (int kf = 0; kf < 8; ++kf)
        #pragma unroll
        for (int r = 0; r < 4; ++r)
          if (key0 + kf * 16 + l4 * 4 + r >= N_TOK) s[kf][r] = -1e30f;
    }
    float pmx = s[0][0];
    #pragma unroll
    for (int kf = 0; kf < 8; ++kf)
      #pragma unroll
      for (int r = 0; r < 4; ++r) pmx = fmaxf(pmx, s[kf][r]);
    pmx = fmaxf(pmx, __shfl_xor(pmx, 16));
    pmx = fmaxf(pmx, __shfl_xor(pmx, 32));
    if (!__all(pmx - mrow <= 8.0f)) {
      const float mi = fmaxf(mrow, pmx);
      const float sc = __expf(mrow - mi);
      mrow = mi;
      lrow *= sc;
      #pragma unroll
      for (int df = 0; df < 4; ++df)
        #pragma unroll
        for (int r = 0; r < 4; ++r) oacc[df][r] *= sc;
    }
    float psum = 0.0f;
    #pragma unroll
    for (int kf = 0; kf < 8; ++kf) {
      const float p0 = __expf(s[kf][0] - mrow);
      const float p1 = __expf(s[kf][1] - mrow);
      const float p2 = __expf(s[kf][2] - mrow);
      const float p3 = __expf(s[kf][3] - mrow);
      psum += (p0 + p1) + (p2 + p3);
      const uint64_t pk = (uint64_t)f2bf(p0) | ((uint64_t)f2bf(p1) << 16)
                        | ((uint64_t)f2bf(p2) << 32) | ((uint64_t)f2bf(p3) << 48);
      const int gr = (kf * 2 + (l4 >> 1)) ^ swz_q;
      *(uint64_t*)(Pls + l15 * 128 + gr * 8 + (l4 & 1) * 4) = pk;
    }
    psum += __shfl_xor(psum, 16);
    psum += __shfl_xor(psum, 32);
    lrow += psum;
    #pragma unroll
    for (int kk = 0; kk < 4; ++kk) {
      const bf16x8 pf = *(const bf16x8*)(Pls + l15 * 128 + (((kk * 4 + l4) ^ swz_q) * 8));
      #pragma unroll
      for (int df = 0; df < 4; ++df) {
        const int d = df * 16 + l15;
        const bf16x8 vfrag = *(const bf16x8*)(Vsm_ + d * KVB_ + (((kk * 4 + l4) ^ (d & 15)) * 8));
        oacc[df] = __builtin_amdgcn_mfma_f32_16x16x32_bf16(vfrag, pf, oacc[df], 0, 0, 0);
      }
    }
  }

  const int q = qt * 128 + w * 16 + l15;
  if (q < N_TOK) {
    const float inv = 1.0f / lrow;
    const int m = (bh >> 4) * N_TOK + q;
    const int hbase = (bh & 15) * 64;
    #pragma unroll
    for (int df = 0; df < 4; ++df)
      #pragma unroll
      for (int r = 0; r < 4; ++r) {
        const int c = hbase + df * 16 + l4 * 4 + r;
        ob[(size_t)m * C_ + c] = f2bf(oacc[df][r] * inv);
      }
  }
}

extern "C" void kernel_launch(void* const* d_in, const int* in_sizes, int n_in,
                              void* d_out, int out_size, void* d_ws, size_t ws_size,
                              hipStream_t stream) {
  const float* x_in   = (const float*)d_in[0];
  const float* ln1_w  = (const float*)d_in[1];
  const float* ln1_b  = (const float*)d_in[2];
  const float* qkv_w  = (const float*)d_in[3];
  const float* qkv_b  = (const float*)d_in[4];
  const float* proj_w = (const float*)d_in[5];
  const float* proj_b = (const float*)d_in[6];
  const float* ln2_w  = (const float*)d_in[7];
  const float* ln2_b  = (const float*)d_in[8];
  const float* fc1_w  = (const float*)d_in[9];
  const float* fc1_b  = (const float*)d_in[10];
  const float* fc2_w  = (const float*)d_in[11];
  const float* fc2_b  = (const float*)d_in[12];
  const float* norm_w = (const float*)d_in[13];
  const float* norm_b = (const float*)d_in[14];

  char* p = (char*)d_ws;
  float*    xbuf = (float*)p;     p += (size_t)MP2_ * C_ * 4;
  uint16_t* hbuf = (uint16_t*)p;  p += (size_t)MP2_ * C_ * 2;
  uint16_t* big  = (uint16_t*)p;  p += (size_t)MP2_ * HID_ * 2;
  uint16_t* wq   = (uint16_t*)p;  p += (size_t)L_ * 3 * C_ * C_ * 2;
  uint16_t* wp   = (uint16_t*)p;  p += (size_t)L_ * C_ * C_ * 2;
  uint16_t* w1   = (uint16_t*)p;  p += (size_t)L_ * HID_ * C_ * 2;
  uint16_t* w2   = (uint16_t*)p;  p += (size_t)L_ * C_ * HID_ * 2;
  uint16_t* qp   = (uint16_t*)p;  p += (size_t)64 * KPAD_ * 64 * 2;
  uint16_t* kp   = (uint16_t*)p;  p += (size_t)64 * KPAD_ * 64 * 2;
  uint16_t* vtp  = (uint16_t*)p;  p += (size_t)64 * 64 * KPAD_ * 2;
  uint16_t* pbuf = (uint16_t*)p;  p += (size_t)4 * PROWS * C_ * 2;  // bf16 partials
  if ((size_t)(p - (char*)d_ws) > ws_size) return;

  hipMemcpyAsync(xbuf, x_in, (size_t)M_TOK * C_ * sizeof(float),
                 hipMemcpyDeviceToDevice, stream);

  auto cvt = [&](const float* src, uint16_t* dst, size_t n) {
    const int n4 = (int)(n / 4);
    cvt_f32_bf16<<<dim3((n4 + 255) / 256), dim3(256), 0, stream>>>(src, dst, n4);
  };
  cvt(qkv_w,  wq, (size_t)L_ * 3 * C_ * C_);
  cvt(proj_w, wp, (size_t)L_ * C_ * C_);
  cvt(fc1_w,  w1, (size_t)L_ * HID_ * C_);
  cvt(fc2_w,  w2, (size_t)L_ * C_ * HID_);

  // layer-0 ln1 (later layers get it fused into reduce_ln)
  ln_fwd<0><<<dim3(M_TOK), dim3(256), 0, stream>>>(xbuf, ln1_w, ln1_b, hbuf);

  for (int lyr = 0; lyr < L_; ++lyr) {
    // qkv: gemm_s (396 blocks, 2/CU) -> per-head panels
    gemm_s<0, 1><<<dim3(396), dim3(512), 0, stream>>>(
        hbuf, wq + (size_t)lyr * 3 * C_ * C_, qkv_b + (size_t)lyr * 3 * C_,
        nullptr, 3 * C_, C_, qp, kp, vtp);
    attn_fwd<<<dim3(64, QT2_), dim3(512), 0, stream>>>(qp, kp, vtp, hbuf);
    // proj: split2 -> bf16 partials; fused reduce + residual + ln2 -> hbuf
    gemm_s<3, 2><<<dim3(264), dim3(512), 0, stream>>>(
        hbuf, wp + (size_t)lyr * C_ * C_, nullptr, pbuf, C_, C_,
        nullptr, nullptr, nullptr);
    reduce_ln<2, 0><<<dim3(M_TOK), dim3(256), 0, stream>>>(
        pbuf, proj_b + (size_t)lyr * C_, xbuf,
        ln2_w + (size_t)lyr * C_, ln2_b + (size_t)lyr * C_, hbuf);
    // fc1: direct, GELU -> big
    gemm_s<1, 1><<<dim3(528), dim3(512), 0, stream>>>(
        hbuf, w1 + (size_t)lyr * HID_ * C_, fc1_b + (size_t)lyr * HID_,
        big, HID_, C_, nullptr, nullptr, nullptr);
    // fc2: split4 -> bf16 partials; fused reduce + (ln1[next] | final norm)
    gemm_s<3, 4><<<dim3(528), dim3(512), 0, stream>>>(
        big, w2 + (size_t)lyr * C_ * HID_, nullptr, pbuf, C_, HID_,
        nullptr, nullptr, nullptr);
    if (lyr < L_ - 1) {
      reduce_ln<4, 0><<<dim3(M_TOK), dim3(256), 0, stream>>>(
          pbuf, fc2_b + (size_t)lyr * C_, xbuf,
          ln1_w + (size_t)(lyr + 1) * C_, ln1_b + (size_t)(lyr + 1) * C_, hbuf);
    } else {
      reduce_ln<4, 1><<<dim3(M_TOK), dim3(256), 0, stream>>>(
          pbuf, fc2_b + (size_t)lyr * C_, xbuf, norm_w, norm_b, d_out);
    }
  }
}